// Round 1
// baseline (1428.481 us; speedup 1.0000x reference)
//
#include <hip/hip_runtime.h>
#include <hip/hip_bf16.h>

#define NU 40000
#define ND 20000
#define FINC 128
#define HIDC 256
#define NHEAD 4
#define DHEAD 64
#define HANOUT 64
#define NEDGE 80000

// ---------------- generic f32 tiled GEMM: C = act(A@B + bias) ----------------
// A: MxK (lda), B: KxN (ldb), C: MxN (ldc). N % 64 == 0, K % 16 == 0.
template<int ACT>
__global__ __launch_bounds__(256)
void gemm_k(const float* __restrict__ A, int lda,
            const float* __restrict__ B, int ldb,
            const float* __restrict__ bias,
            float* __restrict__ C, int ldc,
            int M, int N, int K)
{
  __shared__ float As[16][65];
  __shared__ float Bs[16][65];
  const int tid = threadIdx.x;
  const int tx = tid & 15, ty = tid >> 4;
  const int row0 = blockIdx.y * 64, col0 = blockIdx.x * 64;
  float acc[4][4] = {};
  for (int k0 = 0; k0 < K; k0 += 16) {
#pragma unroll
    for (int i = 0; i < 4; i++) {
      int idx = tid + i * 256;
      int m = idx >> 4, kk = idx & 15;
      int r = row0 + m;
      As[kk][m] = (r < M) ? A[(size_t)r * lda + k0 + kk] : 0.f;
    }
#pragma unroll
    for (int i = 0; i < 4; i++) {
      int idx = tid + i * 256;
      int kk = idx >> 6, n = idx & 63;
      Bs[kk][n] = B[(size_t)(k0 + kk) * ldb + col0 + n];
    }
    __syncthreads();
#pragma unroll
    for (int kk = 0; kk < 16; kk++) {
      float a[4], b[4];
#pragma unroll
      for (int i = 0; i < 4; i++) a[i] = As[kk][ty * 4 + i];
#pragma unroll
      for (int j = 0; j < 4; j++) b[j] = Bs[kk][tx * 4 + j];
#pragma unroll
      for (int i = 0; i < 4; i++)
#pragma unroll
        for (int j = 0; j < 4; j++) acc[i][j] += a[i] * b[j];
    }
    __syncthreads();
  }
#pragma unroll
  for (int i = 0; i < 4; i++) {
    int r = row0 + ty * 4 + i;
    if (r >= M) continue;
#pragma unroll
    for (int j = 0; j < 4; j++) {
      int c = col0 + tx * 4 + j;
      float v = acc[i][j] + bias[c];
      if (ACT == 1) v = fmaxf(v, 0.f);
      C[(size_t)r * ldc + c] = v;
    }
  }
}

// ---------------- HAN: per-node attention logit halves ----------------
__global__ void han_alsd(const float* __restrict__ h,
                         const float* __restrict__ a_s1, const float* __restrict__ a_d1,
                         const float* __restrict__ a_s2, const float* __restrict__ a_d2,
                         float* __restrict__ als1, float* __restrict__ ald1,
                         float* __restrict__ als2, float* __restrict__ ald2)
{
  int t = blockIdx.x * 256 + threadIdx.x;
  if (t >= NU * NHEAD) return;
  int n = t >> 2, hh = t & 3;
  const float* hp = h + (size_t)n * 64 + hh * 16;
  float s1 = 0, d1 = 0, s2 = 0, d2 = 0;
#pragma unroll
  for (int d = 0; d < 16; d++) {
    float v = hp[d];
    s1 += v * a_s1[hh * 16 + d]; d1 += v * a_d1[hh * 16 + d];
    s2 += v * a_s2[hh * 16 + d]; d2 += v * a_d2[hh * 16 + d];
  }
  als1[t] = s1; ald1[t] = d1; als2[t] = s2; ald2[t] = d2;
}

// ---------------- HAN: per-edge leaky_relu + exp, accumulate denom ----------------
__global__ void han_edge_exp(const int* __restrict__ ei, int ne,
                             const float* __restrict__ als, const float* __restrict__ ald,
                             float* __restrict__ ale, float* __restrict__ ssum)
{
  int t = blockIdx.x * 256 + threadIdx.x;
  if (t >= ne * NHEAD) return;
  int e = t >> 2, hh = t & 3;
  int s = ei[e], d = ei[ne + e];
  float al = als[s * 4 + hh] + ald[d * 4 + hh];
  al = (al >= 0.f) ? al : 0.2f * al;     // leaky_relu 0.2
  float ex = expf(al);                    // softmax w/o max-sub (bounded logits)
  ale[t] = ex;
  atomicAdd(&ssum[d * 4 + hh], ex);
}

// ---------------- HAN: weighted scatter o[d] += h[s] * alpha ----------------
__global__ void han_scatter(const int* __restrict__ ei, int ne,
                            const float* __restrict__ h,
                            const float* __restrict__ ale, const float* __restrict__ ssum,
                            float* __restrict__ o)
{
  int t = blockIdx.x * 256 + threadIdx.x;
  if (t >= ne * 64) return;
  int e = t >> 6, j = t & 63, hh = j >> 4;
  int s = ei[e], d = ei[ne + e];
  float w = ale[e * 4 + hh] / (ssum[d * 4 + hh] + 1e-16f);
  atomicAdd(&o[(size_t)d * 64 + j], h[(size_t)s * 64 + j] * w);
}

// ---------------- semantic attention: column sums of tanh(relu(o)@Wk+bk) ----------------
__global__ void sem_colsum(const float* __restrict__ o1, const float* __restrict__ o2,
                           const float* __restrict__ Wk, const float* __restrict__ bk,
                           float* __restrict__ colpart, int nblocks)
{
  int rel = blockIdx.y;
  const float* op = rel ? o2 : o1;
  int j = threadIdx.x & 63, slot = threadIdx.x >> 6;
  float acc = 0.f;
  int base = blockIdx.x * 256;
  for (int it = 0; it < 64; it++) {
    int n = base + it * 4 + slot;
    if (n >= NU) break;
    const float* row = op + (size_t)n * 64;
    float v = bk[j];
    for (int i = 0; i < 64; i++) v += fmaxf(row[i], 0.f) * Wk[i * 64 + j];
    acc += tanhf(v);
  }
  __shared__ float sc[4][64];
  sc[slot][j] = acc;
  __syncthreads();
  if (slot == 0)
    colpart[((size_t)rel * nblocks + blockIdx.x) * 64 + j] = sc[0][j] + sc[1][j] + sc[2][j] + sc[3][j];
}

__global__ void sem_final(const float* __restrict__ colpart, int nblocks,
                          const float* __restrict__ q_sem, float* __restrict__ semv)
{
  int t = threadIdx.x;            // 128 threads
  int r = t >> 6, j = t & 63;
  float s = 0.f;
  for (int b = 0; b < nblocks; b++) s += colpart[((size_t)r * nblocks + b) * 64 + j];
  __shared__ float sv[128];
  sv[t] = s * q_sem[j] * (1.0f / NU);
  __syncthreads();
  if (t == 0) {
    float s0 = 0, s1 = 0;
    for (int i = 0; i < 64; i++) { s0 += sv[i]; s1 += sv[64 + i]; }
    float m = fmaxf(s0, s1);
    float e0 = expf(s0 - m), e1 = expf(s1 - m);
    semv[0] = e0 / (e0 + e1); semv[1] = e1 / (e0 + e1);
  }
}

// ---------------- fold per-head Wk/Wv into the kqv weight ----------------
// Wout[c, h*64+e] = sum_d Wkqv[c, coloff + h*64 + d] * Wh[h,d,e]
__global__ void comb_w(const float* __restrict__ Wkqv, int coloff,
                       const float* __restrict__ Wh, float* __restrict__ Wout)
{
  int t = blockIdx.x * 256 + threadIdx.x;  // c*256 + j
  int c = t >> 8, j = t & 255;
  int hh = j >> 6, e = j & 63;
  float acc = 0.f;
  for (int d = 0; d < 64; d++)
    acc += Wkqv[(size_t)c * 768 + coloff + hh * 64 + d] * Wh[hh * 4096 + d * 64 + e];
  Wout[t] = acc;
}

__global__ void comb_b(const float* __restrict__ bkqv, int coloff,
                       const float* __restrict__ Wh, float* __restrict__ bout)
{
  int j = threadIdx.x;  // 256
  int hh = j >> 6, e = j & 63;
  float acc = 0.f;
  for (int d = 0; d < 64; d++)
    acc += bkqv[coloff + hh * 64 + d] * Wh[hh * 4096 + d * 64 + e];
  bout[j] = acc;
}

// ---------------- HGT: per-edge q.k dot + exp, accumulate denom ----------------
__global__ void hgt_edge_exp(const int* __restrict__ ei, int ne,
                             const float* __restrict__ q,
                             const float* __restrict__ kp,
                             const float* __restrict__ p,
                             float* __restrict__ ae, float* __restrict__ ssum)
{
  int t = blockIdx.x * 256 + threadIdx.x;
  if (t >= ne * NHEAD) return;
  int e = t >> 2, hh = t & 3;
  int s = ei[e], d = ei[ne + e];
  const float4* qv = (const float4*)(q + (size_t)d * HIDC + hh * DHEAD);
  const float4* kv = (const float4*)(kp + (size_t)s * HIDC + hh * DHEAD);
  float acc = 0.f;
#pragma unroll
  for (int i = 0; i < 16; i++) {
    float4 a = qv[i], b = kv[i];
    acc += a.x * b.x + a.y * b.y + a.z * b.z + a.w * b.w;
  }
  float ex = expf(acc * p[hh] * 0.125f);  // * p * 1/sqrt(64)
  ae[t] = ex;
  atomicAdd(&ssum[d * 4 + hh], ex);
}

// ---------------- HGT: weighted scatter out[d] += vp[s] * alpha ----------------
__global__ void hgt_scatter(const int* __restrict__ ei, int ne,
                            const float* __restrict__ vp,
                            const float* __restrict__ ae, const float* __restrict__ ssum,
                            float* __restrict__ out)
{
  int t = blockIdx.x * 256 + threadIdx.x;
  if (t >= ne * HIDC) return;
  int e = t >> 8, j = t & 255, hh = j >> 6;
  int s = ei[e], d = ei[ne + e];
  float w = ae[e * 4 + hh] / (ssum[d * 4 + hh] + 1e-16f);
  atomicAdd(&out[(size_t)d * HIDC + j], vp[(size_t)s * HIDC + j] * w);
}

// ---------------- epilogues ----------------
__global__ void gelu_inplace(float* __restrict__ x, int n)
{
  int t = blockIdx.x * 256 + threadIdx.x;
  if (t < n) {
    float v = x[t];
    x[t] = 0.5f * v * (1.f + erff(v * 0.70710678118654752f));
  }
}

__global__ void fill_ref_cols(const float* __restrict__ o1, const float* __restrict__ o2,
                              const float* __restrict__ semv, float* __restrict__ afin)
{
  int t = blockIdx.x * 256 + threadIdx.x;  // n*64 + j
  if (t >= NU * 64) return;
  int n = t >> 6, j = t & 63;
  float v = semv[0] * fmaxf(o1[t], 0.f) + semv[1] * fmaxf(o2[t], 0.f);
  afin[(size_t)n * 320 + 256 + j] = v;
}

__global__ void skip_mix(float* __restrict__ afin, const float* __restrict__ xu,
                         const float* __restrict__ skipp)
{
  int t = blockIdx.x * 256 + threadIdx.x;  // n*256 + j
  if (t >= NU * HIDC) return;
  int n = t >> 8, j = t & 255;
  float su = 1.f / (1.f + expf(-skipp[0]));
  float* pa = &afin[(size_t)n * 320 + j];
  *pa = su * (*pa) + (1.f - su) * xu[t];
}

// ------------------------------------------------------------------
extern "C" void kernel_launch(void* const* d_in, const int* in_sizes, int n_in,
                              void* d_out, int out_size, void* d_ws, size_t ws_size,
                              hipStream_t stream)
{
  (void)in_sizes; (void)n_in; (void)out_size; (void)ws_size;
  const float* x_user     = (const float*)d_in[0];
  const float* x_drug     = (const float*)d_in[1];
  const float* x_user_ref = (const float*)d_in[2];
  const int*   ei_du      = (const int*)d_in[4];
  const int*   ei_uu      = (const int*)d_in[5];
  const int*   ei_r1      = (const int*)d_in[6];
  const int*   ei_r2      = (const int*)d_in[7];
  const float* W_han      = (const float*)d_in[8];
  const float* b_han      = (const float*)d_in[9];
  const float* a_src_r1   = (const float*)d_in[10];
  const float* a_dst_r1   = (const float*)d_in[11];
  const float* a_src_r2   = (const float*)d_in[12];
  const float* a_dst_r2   = (const float*)d_in[13];
  const float* Wk_sem     = (const float*)d_in[14];
  const float* bk_sem     = (const float*)d_in[15];
  const float* q_sem      = (const float*)d_in[16];
  const float* W_in_user  = (const float*)d_in[17];
  const float* b_in_user  = (const float*)d_in[18];
  const float* W_in_drug  = (const float*)d_in[19];
  const float* b_in_drug  = (const float*)d_in[20];
  const float* W_kqv_user = (const float*)d_in[21];
  const float* b_kqv_user = (const float*)d_in[22];
  const float* W_kqv_drug = (const float*)d_in[23];
  const float* b_kqv_drug = (const float*)d_in[24];
  const float* Wk_du      = (const float*)d_in[28];
  const float* Wv_du      = (const float*)d_in[29];
  const float* p_du       = (const float*)d_in[30];
  const float* Wk_uu      = (const float*)d_in[31];
  const float* Wv_uu      = (const float*)d_in[32];
  const float* p_uu       = (const float*)d_in[33];
  const float* W_out_user = (const float*)d_in[34];
  const float* b_out_user = (const float*)d_in[35];
  const float* skip_user  = (const float*)d_in[38];
  const float* W_fin      = (const float*)d_in[40];
  const float* b_fin      = (const float*)d_in[41];
  float* out = (float*)d_out;

  // ---------------- workspace layout (floats) ----------------
  float* w = (float*)d_ws;
  size_t off = 0;
  auto alloc = [&](size_t n) { float* p = w + off; off += n; return p; };
  float* h       = alloc((size_t)NU * 64);
  float* als1    = alloc((size_t)NU * 4);
  float* ald1    = alloc((size_t)NU * 4);
  float* als2    = alloc((size_t)NU * 4);
  float* ald2    = alloc((size_t)NU * 4);
  float* s1a     = alloc((size_t)NU * 4);   // adjacent to s1b for one memset
  float* s1b     = alloc((size_t)NU * 4);
  float* ale     = alloc((size_t)NEDGE * 4);
  float* o1      = alloc((size_t)NU * 64);  // adjacent to o2 for one memset
  float* o2      = alloc((size_t)NU * 64);
  const int nblocks_cs = (NU + 255) / 256;  // 157
  float* colpart = alloc((size_t)2 * nblocks_cs * 64);
  float* semv    = alloc(16);
  float* Wku     = alloc(65536);
  float* Wvu     = alloc(65536);
  float* Wkd     = alloc(65536);
  float* Wvd     = alloc(65536);
  float* bku     = alloc(256);
  float* bvu     = alloc(256);
  float* bkd     = alloc(256);
  float* bvd     = alloc(256);
  float* xu      = alloc((size_t)NU * HIDC);
  float* xd      = alloc((size_t)ND * HIDC);
  float* qu      = alloc((size_t)NU * HIDC);   // later reused as hout
  float* kpu     = alloc((size_t)NU * HIDC);   // kpu+kpd block later reused as afin
  float* kpd     = alloc((size_t)ND * HIDC);
  float* vpu     = alloc((size_t)NU * HIDC);
  float* vpd     = alloc((size_t)ND * HIDC);
  float* ae_du   = alloc((size_t)NEDGE * 4);
  float* ae_uu   = alloc((size_t)NEDGE * 4);
  float* s2      = alloc((size_t)NU * 4);
  float* hout = qu;    // safe: qu last read in hgt_edge_exp, hout written after
  float* afin = kpu;   // safe: kp last read in hgt_edge_exp; afin 12.8M <= 15.36M

  const int B = 256;
  dim3 blk(B);

  // ===== HAN branch =====
  hipMemsetAsync(s1a, 0, (size_t)NU * 8 * sizeof(float), stream);   // s1a+s1b
  hipMemsetAsync(o1, 0, (size_t)NU * 128 * sizeof(float), stream);  // o1+o2

  gemm_k<0><<<dim3(HANOUT / 64, (NU + 63) / 64), blk, 0, stream>>>(
      x_user_ref, FINC, W_han, HANOUT, b_han, h, HANOUT, NU, HANOUT, FINC);

  han_alsd<<<(NU * 4 + B - 1) / B, blk, 0, stream>>>(
      h, a_src_r1, a_dst_r1, a_src_r2, a_dst_r2, als1, ald1, als2, ald2);

  han_edge_exp<<<(NEDGE * 4 + B - 1) / B, blk, 0, stream>>>(ei_r1, NEDGE, als1, ald1, ale, s1a);
  han_scatter <<<(NEDGE * 64 + B - 1) / B, blk, 0, stream>>>(ei_r1, NEDGE, h, ale, s1a, o1);
  han_edge_exp<<<(NEDGE * 4 + B - 1) / B, blk, 0, stream>>>(ei_r2, NEDGE, als2, ald2, ale, s1b);
  han_scatter <<<(NEDGE * 64 + B - 1) / B, blk, 0, stream>>>(ei_r2, NEDGE, h, ale, s1b, o2);

  sem_colsum<<<dim3(nblocks_cs, 2), blk, 0, stream>>>(o1, o2, Wk_sem, bk_sem, colpart, nblocks_cs);
  sem_final<<<1, 128, 0, stream>>>(colpart, nblocks_cs, q_sem, semv);

  // ===== HGT branch =====
  comb_w<<<256, blk, 0, stream>>>(W_kqv_user, 0,   Wk_uu, Wku);
  comb_w<<<256, blk, 0, stream>>>(W_kqv_user, 512, Wv_uu, Wvu);
  comb_w<<<256, blk, 0, stream>>>(W_kqv_drug, 0,   Wk_du, Wkd);
  comb_w<<<256, blk, 0, stream>>>(W_kqv_drug, 512, Wv_du, Wvd);
  comb_b<<<1, blk, 0, stream>>>(b_kqv_user, 0,   Wk_uu, bku);
  comb_b<<<1, blk, 0, stream>>>(b_kqv_user, 512, Wv_uu, bvu);
  comb_b<<<1, blk, 0, stream>>>(b_kqv_drug, 0,   Wk_du, bkd);
  comb_b<<<1, blk, 0, stream>>>(b_kqv_drug, 512, Wv_du, bvd);

  gemm_k<1><<<dim3(HIDC / 64, (NU + 63) / 64), blk, 0, stream>>>(
      x_user, FINC, W_in_user, HIDC, b_in_user, xu, HIDC, NU, HIDC, FINC);
  gemm_k<1><<<dim3(HIDC / 64, (ND + 63) / 64), blk, 0, stream>>>(
      x_drug, FINC, W_in_drug, HIDC, b_in_drug, xd, HIDC, ND, HIDC, FINC);

  gemm_k<0><<<dim3(HIDC / 64, (NU + 63) / 64), blk, 0, stream>>>(
      xu, HIDC, W_kqv_user + 256, 768, b_kqv_user + 256, qu, HIDC, NU, HIDC, HIDC);
  gemm_k<0><<<dim3(HIDC / 64, (NU + 63) / 64), blk, 0, stream>>>(
      xu, HIDC, Wku, HIDC, bku, kpu, HIDC, NU, HIDC, HIDC);
  gemm_k<0><<<dim3(HIDC / 64, (NU + 63) / 64), blk, 0, stream>>>(
      xu, HIDC, Wvu, HIDC, bvu, vpu, HIDC, NU, HIDC, HIDC);
  gemm_k<0><<<dim3(HIDC / 64, (ND + 63) / 64), blk, 0, stream>>>(
      xd, HIDC, Wkd, HIDC, bkd, kpd, HIDC, ND, HIDC, HIDC);
  gemm_k<0><<<dim3(HIDC / 64, (ND + 63) / 64), blk, 0, stream>>>(
      xd, HIDC, Wvd, HIDC, bvd, vpd, HIDC, ND, HIDC, HIDC);

  hipMemsetAsync(s2, 0, (size_t)NU * 4 * sizeof(float), stream);
  hgt_edge_exp<<<(NEDGE * 4 + B - 1) / B, blk, 0, stream>>>(ei_du, NEDGE, qu, kpd, p_du, ae_du, s2);
  hgt_edge_exp<<<(NEDGE * 4 + B - 1) / B, blk, 0, stream>>>(ei_uu, NEDGE, qu, kpu, p_uu, ae_uu, s2);

  hipMemsetAsync(hout, 0, (size_t)NU * HIDC * sizeof(float), stream);  // after edge_exp reads qu
  hgt_scatter<<<(NEDGE * HIDC + B - 1) / B, blk, 0, stream>>>(ei_du, NEDGE, vpd, ae_du, s2, hout);
  hgt_scatter<<<(NEDGE * HIDC + B - 1) / B, blk, 0, stream>>>(ei_uu, NEDGE, vpu, ae_uu, s2, hout);

  gelu_inplace<<<(NU * HIDC + B - 1) / B, blk, 0, stream>>>(hout, NU * HIDC);

  fill_ref_cols<<<(NU * 64 + B - 1) / B, blk, 0, stream>>>(o1, o2, semv, afin);

  gemm_k<0><<<dim3(HIDC / 64, (NU + 63) / 64), blk, 0, stream>>>(
      hout, HIDC, W_out_user, HIDC, b_out_user, afin, 320, NU, HIDC, HIDC);

  skip_mix<<<(NU * HIDC + B - 1) / B, blk, 0, stream>>>(afin, xu, skip_user);

  gemm_k<0><<<dim3(HIDC / 64, (NU + 63) / 64), blk, 0, stream>>>(
      afin, 320, W_fin, HIDC, b_fin, out, HIDC, NU, HIDC, 320);
}

// Round 2
// 752.527 us; speedup vs baseline: 1.8982x; 1.8982x over previous
//
#include <hip/hip_runtime.h>
#include <hip/hip_bf16.h>

#define NU 40000
#define ND 20000
#define NUP 40064   // 313*128
#define NDP 20096   // 157*128
#define FINC 128
#define HIDC 256
#define NHEAD 4
#define HANOUT 64
#define NEDGE 80000

typedef __attribute__((ext_vector_type(8))) short bf16x8;
typedef __attribute__((ext_vector_type(4))) float f32x4;

static __device__ __forceinline__ float b2f(unsigned short u) {
  union { unsigned int u; float f; } x; x.u = (unsigned int)u << 16; return x.f;
}
static __device__ __forceinline__ unsigned short f2b(float f) {
  union { float f; unsigned int u; } x; x.f = f;
  unsigned int r = x.u + 0x7FFFu + ((x.u >> 16) & 1u);
  return (unsigned short)(r >> 16);
}

static __device__ __forceinline__ void gload_lds16(const void* g, void* l) {
  __builtin_amdgcn_global_load_lds((const __attribute__((address_space(1))) unsigned int*)g,
                                   (__attribute__((address_space(3))) unsigned int*)l, 16, 0, 0);
}

// ============ bf16 MFMA GEMM: C = act(A @ Bt^T + bias) ============
// A: [Mpad][K] bf16 (row-major, stride K). Bt: [Npad][K] bf16 (= B transposed).
// grid = (Npad/128, Mpad/128), 256 threads (4 waves, 2x2).
// Cf (f32, ldcf) optional; Cb (bf16, ldcb) optional, zero-filled for rows>=M.
template<int ACT>
__global__ __launch_bounds__(256)
void gemm_bf16(const unsigned short* __restrict__ A,
               const unsigned short* __restrict__ Bt,
               const float* __restrict__ bias,
               float* __restrict__ Cf, int ldcf,
               unsigned short* __restrict__ Cb, int ldcb,
               int M, int N, int K)
{
  __shared__ __attribute__((aligned(128))) unsigned short lds[16384]; // A 8192 + B 8192
  unsigned short* ldsA = lds;
  unsigned short* ldsB = lds + 8192;

  const int tid  = threadIdx.x;
  const int lane = tid & 63, wv = tid >> 6;
  const int row0 = blockIdx.y * 128, col0 = blockIdx.x * 128;

  // staging geometry: wave w, inst i covers rows w*32+i*8+(lane>>3), slot lane&7
  const int rS = wv * 32 + (lane >> 3);
  const int sS = (lane & 7) ^ (lane >> 3);          // pre-swizzled source slot

  const int lr = lane & 15, lk = lane >> 4;
  const int wr = wv >> 1, wc = wv & 1;
  const int swz = lr & 7;

  f32x4 acc[4][4] = {};

  for (int k0 = 0; k0 < K; k0 += 64) {
#pragma unroll
    for (int i = 0; i < 4; i++) {
      size_t ga = (size_t)(row0 + rS + i * 8) * K + k0 + sS * 8;
      gload_lds16(A + ga, ldsA + wv * 2048 + i * 512);
      size_t gb = (size_t)(col0 + rS + i * 8) * K + k0 + sS * 8;
      gload_lds16(Bt + gb, ldsB + wv * 2048 + i * 512);
    }
    __syncthreads();
#pragma unroll
    for (int half = 0; half < 2; half++) {
      const int k8 = half * 4 + lk;
      const int so = (k8 ^ swz) << 3;
      bf16x8 av[4], bv[4];
#pragma unroll
      for (int m = 0; m < 4; m++)
        av[m] = *(const bf16x8*)&ldsA[(wr * 64 + m * 16 + lr) * 64 + so];
#pragma unroll
      for (int n = 0; n < 4; n++)
        bv[n] = *(const bf16x8*)&ldsB[(wc * 64 + n * 16 + lr) * 64 + so];
#pragma unroll
      for (int m = 0; m < 4; m++)
#pragma unroll
        for (int n = 0; n < 4; n++)
          acc[m][n] = __builtin_amdgcn_mfma_f32_16x16x32_bf16(av[m], bv[n], acc[m][n], 0, 0, 0);
    }
    __syncthreads();
  }

#pragma unroll
  for (int n = 0; n < 4; n++) {
    int col = col0 + wc * 64 + n * 16 + lr;
    bool cok = col < N;
    float bi = cok ? bias[col] : 0.f;
#pragma unroll
    for (int m = 0; m < 4; m++) {
#pragma unroll
      for (int g = 0; g < 4; g++) {
        int row = row0 + wr * 64 + m * 16 + lk * 4 + g;
        float v = acc[m][n][g] + bi;
        if (ACT == 1) v = fmaxf(v, 0.f);
        if (cok) {
          if (Cf && row < M) Cf[(size_t)row * ldcf + col] = v;
          if (Cb) Cb[(size_t)row * ldcb + col] = f2b(row < M ? v : 0.f);
        }
      }
    }
  }
}

// ============ prep kernels ============
// f32 [M][C] -> bf16 [Mpad][C], zero pad rows
__global__ void conv_pad(const float* __restrict__ in, unsigned short* __restrict__ out,
                         int M, int C, int total)
{
  int t = blockIdx.x * 256 + threadIdx.x;
  if (t >= total) return;
  int r = t / C;
  out[t] = (r < M) ? f2b(in[t]) : 0;
}

// W [K][N] (stride ldw, col offset) -> Bt bf16 [Npad][K], zero pad
__global__ void transp_conv(const float* __restrict__ W, int ldw, int coloff,
                            unsigned short* __restrict__ Bt, int K, int N, int total)
{
  int t = blockIdx.x * 256 + threadIdx.x;
  if (t >= total) return;
  int n = t / K, k = t - n * K;
  Bt[t] = (n < N) ? f2b(W[(size_t)k * ldw + coloff + n]) : 0;
}

// folded per-head weight, transposed bf16: Bt[n=hh*64+e][c] = sum_d Wkqv[c][off+hh*64+d]*Wh[hh][d][e]
__global__ void comb_w_t(const float* __restrict__ Wkqv, int coloff,
                         const float* __restrict__ Wh, unsigned short* __restrict__ Bt)
{
  int t = blockIdx.x * 256 + threadIdx.x;  // n*256 + c
  int n = t >> 8, c = t & 255;
  int hh = n >> 6, e = n & 63;
  float acc = 0.f;
  for (int d = 0; d < 64; d++)
    acc += Wkqv[(size_t)c * 768 + coloff + hh * 64 + d] * Wh[hh * 4096 + d * 64 + e];
  Bt[t] = f2b(acc);
}

__global__ void comb_b(const float* __restrict__ bkqv, int coloff,
                       const float* __restrict__ Wh, float* __restrict__ bout)
{
  int j = threadIdx.x;  // 256
  int hh = j >> 6, e = j & 63;
  float acc = 0.f;
  for (int d = 0; d < 64; d++)
    acc += bkqv[coloff + hh * 64 + d] * Wh[hh * 4096 + d * 64 + e];
  bout[j] = acc;
}

// ============ HAN ============
__global__ void han_alsd(const float* __restrict__ h,
                         const float* __restrict__ a_s1, const float* __restrict__ a_d1,
                         const float* __restrict__ a_s2, const float* __restrict__ a_d2,
                         float* __restrict__ als1, float* __restrict__ ald1,
                         float* __restrict__ als2, float* __restrict__ ald2)
{
  int t = blockIdx.x * 256 + threadIdx.x;
  if (t >= NU * NHEAD) return;
  int n = t >> 2, hh = t & 3;
  const float* hp = h + (size_t)n * 64 + hh * 16;
  float s1 = 0, d1 = 0, s2 = 0, d2 = 0;
#pragma unroll
  for (int d = 0; d < 16; d++) {
    float v = hp[d];
    s1 += v * a_s1[hh * 16 + d]; d1 += v * a_d1[hh * 16 + d];
    s2 += v * a_s2[hh * 16 + d]; d2 += v * a_d2[hh * 16 + d];
  }
  als1[t] = s1; ald1[t] = d1; als2[t] = s2; ald2[t] = d2;
}

__global__ void han_edge_exp(const int* __restrict__ ei, int ne,
                             const float* __restrict__ als, const float* __restrict__ ald,
                             float* __restrict__ ale, float* __restrict__ ssum)
{
  int t = blockIdx.x * 256 + threadIdx.x;
  if (t >= ne * NHEAD) return;
  int e = t >> 2, hh = t & 3;
  int s = ei[e], d = ei[ne + e];
  float al = als[s * 4 + hh] + ald[d * 4 + hh];
  al = (al >= 0.f) ? al : 0.2f * al;
  float ex = expf(al);
  ale[t] = ex;
  atomicAdd(&ssum[d * 4 + hh], ex);
}

__global__ void han_scatter(const int* __restrict__ ei, int ne,
                            const float* __restrict__ h,
                            const float* __restrict__ ale, const float* __restrict__ ssum,
                            float* __restrict__ o)
{
  int t = blockIdx.x * 256 + threadIdx.x;
  if (t >= ne * 64) return;
  int e = t >> 6, j = t & 63, hh = j >> 4;
  int s = ei[e], d = ei[ne + e];
  float w = ale[e * 4 + hh] / (ssum[d * 4 + hh] + 1e-16f);
  atomicAdd(&o[(size_t)d * 64 + j], h[(size_t)s * 64 + j] * w);
}

__global__ void sem_colsum(const float* __restrict__ o1, const float* __restrict__ o2,
                           const float* __restrict__ Wk, const float* __restrict__ bk,
                           float* __restrict__ colpart, int nblocks)
{
  int rel = blockIdx.y;
  const float* op = rel ? o2 : o1;
  int j = threadIdx.x & 63, slot = threadIdx.x >> 6;
  float acc = 0.f;
  int base = blockIdx.x * 256;
  for (int it = 0; it < 64; it++) {
    int n = base + it * 4 + slot;
    if (n >= NU) break;
    const float* row = op + (size_t)n * 64;
    float v = bk[j];
    for (int i = 0; i < 64; i++) v += fmaxf(row[i], 0.f) * Wk[i * 64 + j];
    acc += tanhf(v);
  }
  __shared__ float sc[4][64];
  sc[slot][j] = acc;
  __syncthreads();
  if (slot == 0)
    colpart[((size_t)rel * nblocks + blockIdx.x) * 64 + j] = sc[0][j] + sc[1][j] + sc[2][j] + sc[3][j];
}

__global__ void sem_final(const float* __restrict__ colpart, int nblocks,
                          const float* __restrict__ q_sem, float* __restrict__ semv)
{
  int t = threadIdx.x;            // 128
  int r = t >> 6, j = t & 63;
  float s = 0.f;
  for (int b = 0; b < nblocks; b++) s += colpart[((size_t)r * nblocks + b) * 64 + j];
  __shared__ float sv[128];
  sv[t] = s * q_sem[j] * (1.0f / NU);
  __syncthreads();
  if (t == 0) {
    float s0 = 0, s1 = 0;
    for (int i = 0; i < 64; i++) { s0 += sv[i]; s1 += sv[64 + i]; }
    float m = fmaxf(s0, s1);
    float e0 = expf(s0 - m), e1 = expf(s1 - m);
    semv[0] = e0 / (e0 + e1); semv[1] = e1 / (e0 + e1);
  }
}

// ============ HGT edge kernels (bf16 inputs) ============
__global__ void hgt_edge_exp(const int* __restrict__ ei, int ne,
                             const unsigned short* __restrict__ q,
                             const unsigned short* __restrict__ kp,
                             const float* __restrict__ p,
                             float* __restrict__ ae, float* __restrict__ ssum)
{
  int t = blockIdx.x * 256 + threadIdx.x;
  if (t >= ne * NHEAD) return;
  int e = t >> 2, hh = t & 3;
  int s = ei[e], d = ei[ne + e];
  const uint4* qv = (const uint4*)(q + (size_t)d * HIDC + hh * 64);
  const uint4* kv = (const uint4*)(kp + (size_t)s * HIDC + hh * 64);
  float acc = 0.f;
#pragma unroll
  for (int i = 0; i < 8; i++) {
    uint4 a = qv[i], b = kv[i];
    unsigned int aw[4] = {a.x, a.y, a.z, a.w};
    unsigned int bw[4] = {b.x, b.y, b.z, b.w};
#pragma unroll
    for (int u = 0; u < 4; u++) {
      acc += b2f((unsigned short)(aw[u] & 0xffff)) * b2f((unsigned short)(bw[u] & 0xffff));
      acc += b2f((unsigned short)(aw[u] >> 16))    * b2f((unsigned short)(bw[u] >> 16));
    }
  }
  float ex = expf(acc * p[hh] * 0.125f);
  ae[t] = ex;
  atomicAdd(&ssum[d * 4 + hh], ex);
}

__global__ void hgt_scatter(const int* __restrict__ ei, int ne,
                            const unsigned short* __restrict__ vp,
                            const float* __restrict__ ae, const float* __restrict__ ssum,
                            float* __restrict__ out)
{
  int t = blockIdx.x * 256 + threadIdx.x;
  if (t >= ne * HIDC) return;
  int e = t >> 8, j = t & 255, hh = j >> 6;
  int s = ei[e], d = ei[ne + e];
  float w = ae[e * 4 + hh] / (ssum[d * 4 + hh] + 1e-16f);
  atomicAdd(&out[(size_t)d * HIDC + j], b2f(vp[(size_t)s * HIDC + j]) * w);
}

// ============ epilogues ============
__global__ void gelu_conv(const float* __restrict__ in, unsigned short* __restrict__ outb,
                          int total)
{
  int t = blockIdx.x * 256 + threadIdx.x;
  if (t >= total) return;
  int r = t >> 8;
  float v = 0.f;
  if (r < NU) {
    float x = in[t];
    v = 0.5f * x * (1.f + erff(x * 0.70710678118654752f));
  }
  outb[t] = f2b(v);
}

__global__ void fill_ref_b(const float* __restrict__ o1, const float* __restrict__ o2,
                           const float* __restrict__ semv, unsigned short* __restrict__ afinb)
{
  int t = blockIdx.x * 256 + threadIdx.x;  // n*64 + j
  if (t >= NU * 64) return;
  int n = t >> 6, j = t & 63;
  float v = semv[0] * fmaxf(o1[t], 0.f) + semv[1] * fmaxf(o2[t], 0.f);
  afinb[(size_t)n * 320 + 256 + j] = f2b(v);
}

__global__ void skip_mix_b(const float* __restrict__ afin, const float* __restrict__ xu,
                           const float* __restrict__ skipp, unsigned short* __restrict__ afinb)
{
  int t = blockIdx.x * 256 + threadIdx.x;  // n*256 + j
  if (t >= NU * HIDC) return;
  int n = t >> 8, j = t & 255;
  float su = 1.f / (1.f + expf(-skipp[0]));
  float v = su * afin[(size_t)n * 320 + j] + (1.f - su) * xu[t];
  afinb[(size_t)n * 320 + j] = f2b(v);
}

// ------------------------------------------------------------------
extern "C" void kernel_launch(void* const* d_in, const int* in_sizes, int n_in,
                              void* d_out, int out_size, void* d_ws, size_t ws_size,
                              hipStream_t stream)
{
  (void)in_sizes; (void)n_in; (void)out_size; (void)ws_size;
  const float* x_user     = (const float*)d_in[0];
  const float* x_drug     = (const float*)d_in[1];
  const float* x_user_ref = (const float*)d_in[2];
  const int*   ei_du      = (const int*)d_in[4];
  const int*   ei_uu      = (const int*)d_in[5];
  const int*   ei_r1      = (const int*)d_in[6];
  const int*   ei_r2      = (const int*)d_in[7];
  const float* W_han      = (const float*)d_in[8];
  const float* b_han      = (const float*)d_in[9];
  const float* a_src_r1   = (const float*)d_in[10];
  const float* a_dst_r1   = (const float*)d_in[11];
  const float* a_src_r2   = (const float*)d_in[12];
  const float* a_dst_r2   = (const float*)d_in[13];
  const float* Wk_sem     = (const float*)d_in[14];
  const float* bk_sem     = (const float*)d_in[15];
  const float* q_sem      = (const float*)d_in[16];
  const float* W_in_user  = (const float*)d_in[17];
  const float* b_in_user  = (const float*)d_in[18];
  const float* W_in_drug  = (const float*)d_in[19];
  const float* b_in_drug  = (const float*)d_in[20];
  const float* W_kqv_user = (const float*)d_in[21];
  const float* b_kqv_user = (const float*)d_in[22];
  const float* W_kqv_drug = (const float*)d_in[23];
  const float* b_kqv_drug = (const float*)d_in[24];
  const float* Wk_du      = (const float*)d_in[28];
  const float* Wv_du      = (const float*)d_in[29];
  const float* p_du       = (const float*)d_in[30];
  const float* Wk_uu      = (const float*)d_in[31];
  const float* Wv_uu      = (const float*)d_in[32];
  const float* p_uu       = (const float*)d_in[33];
  const float* W_out_user = (const float*)d_in[34];
  const float* b_out_user = (const float*)d_in[35];
  const float* skip_user  = (const float*)d_in[38];
  const float* W_fin      = (const float*)d_in[40];
  const float* b_fin      = (const float*)d_in[41];
  float* out = (float*)d_out;

  // ---------------- workspace layout (bytes) ----------------
  char* base = (char*)d_ws;
  size_t off = 0;
  auto alloc = [&](size_t bytes) { char* p = base + off; off += (bytes + 255) & ~(size_t)255; return p; };

  float* h       = (float*)alloc((size_t)NU * 64 * 4);
  float* als1    = (float*)alloc((size_t)NU * 4 * 4);
  float* ald1    = (float*)alloc((size_t)NU * 4 * 4);
  float* als2    = (float*)alloc((size_t)NU * 4 * 4);
  float* ald2    = (float*)alloc((size_t)NU * 4 * 4);
  float* s1a     = (float*)alloc((size_t)NU * 4 * 4);
  float* s1b     = (float*)alloc((size_t)NU * 4 * 4);
  float* ale     = (float*)alloc((size_t)NEDGE * 4 * 4);
  float* o1      = (float*)alloc((size_t)NU * 64 * 4);
  float* o2      = (float*)alloc((size_t)NU * 64 * 4);
  const int nblocks_cs = (NU + 255) / 256;  // 157
  float* colpart = (float*)alloc((size_t)2 * nblocks_cs * 64 * 4);
  float* semv    = (float*)alloc(64);
  float* bku     = (float*)alloc(1024);
  float* bvu     = (float*)alloc(1024);
  float* bkd     = (float*)alloc(1024);
  float* bvd     = (float*)alloc(1024);
  float* xu      = (float*)alloc((size_t)NU * 256 * 4);
  float* ae_du   = (float*)alloc((size_t)NEDGE * 4 * 4);
  float* ae_uu   = (float*)alloc((size_t)NEDGE * 4 * 4);
  float* s2      = (float*)alloc((size_t)NU * 4 * 4);

  // region P: bf16 projections; later aliased by hout (f32)
  unsigned short* qub  = (unsigned short*)alloc((size_t)NUP * 256 * 2);
  unsigned short* kpub = (unsigned short*)alloc((size_t)NUP * 256 * 2);
  unsigned short* vpub = (unsigned short*)alloc((size_t)NUP * 256 * 2);
  unsigned short* kpdb = (unsigned short*)alloc((size_t)NDP * 256 * 2);
  unsigned short* vpdb = (unsigned short*)alloc((size_t)NDP * 256 * 2);
  float* hout = (float*)qub;  // 40.96MB <= qub+kpub (41MB); written after edge_exp reads

  // region F: afin f32; earlier aliased by xub2/xdb2 (dead before afin written)
  float* afin = (float*)alloc((size_t)NU * 320 * 4);
  unsigned short* xub2 = (unsigned short*)afin;
  unsigned short* xdb2 = (unsigned short*)afin + (size_t)NUP * 256;

  // region H: houtb bf16; earlier aliased by xrb
  unsigned short* houtb = (unsigned short*)alloc((size_t)NUP * 256 * 2);
  unsigned short* xrb   = houtb;

  // region AB: afinb bf16; earlier aliased by xub/xdb
  unsigned short* afinb = (unsigned short*)alloc((size_t)NUP * 320 * 2);
  unsigned short* xub   = afinb;
  unsigned short* xdb   = afinb + (size_t)NUP * 128;

  // weights (bf16, transposed)
  unsigned short* Btu_in = (unsigned short*)alloc(256 * 128 * 2);
  unsigned short* Btd_in = (unsigned short*)alloc(256 * 128 * 2);
  unsigned short* Btq    = (unsigned short*)alloc(256 * 256 * 2);
  unsigned short* Btku   = (unsigned short*)alloc(256 * 256 * 2);
  unsigned short* Btvu   = (unsigned short*)alloc(256 * 256 * 2);
  unsigned short* Btkd   = (unsigned short*)alloc(256 * 256 * 2);
  unsigned short* Btvd   = (unsigned short*)alloc(256 * 256 * 2);
  unsigned short* Bto    = (unsigned short*)alloc(256 * 256 * 2);
  unsigned short* Btf    = (unsigned short*)alloc(256 * 320 * 2);
  unsigned short* Bth    = (unsigned short*)alloc(128 * 128 * 2);

  const int B = 256;
  dim3 blk(B);
  auto g1 = [](size_t n) { return dim3((unsigned)((n + 255) / 256)); };

  // ===== prep: converts + weight transforms =====
  conv_pad<<<g1((size_t)NUP * 128), blk, 0, stream>>>(x_user, xub, NU, 128, NUP * 128);
  conv_pad<<<g1((size_t)NDP * 128), blk, 0, stream>>>(x_drug, xdb, ND, 128, NDP * 128);
  conv_pad<<<g1((size_t)NUP * 128), blk, 0, stream>>>(x_user_ref, xrb, NU, 128, NUP * 128);

  transp_conv<<<g1(256 * 128), blk, 0, stream>>>(W_in_user, 256, 0, Btu_in, 128, 256, 256 * 128);
  transp_conv<<<g1(256 * 128), blk, 0, stream>>>(W_in_drug, 256, 0, Btd_in, 128, 256, 256 * 128);
  transp_conv<<<g1(256 * 256), blk, 0, stream>>>(W_kqv_user, 768, 256, Btq, 256, 256, 256 * 256);
  transp_conv<<<g1(256 * 256), blk, 0, stream>>>(W_out_user, 256, 0, Bto, 256, 256, 256 * 256);
  transp_conv<<<g1(256 * 320), blk, 0, stream>>>(W_fin, 256, 0, Btf, 320, 256, 256 * 320);
  transp_conv<<<g1(128 * 128), blk, 0, stream>>>(W_han, 64, 0, Bth, 128, 64, 128 * 128);

  comb_w_t<<<256, blk, 0, stream>>>(W_kqv_user, 0,   Wk_uu, Btku);
  comb_w_t<<<256, blk, 0, stream>>>(W_kqv_user, 512, Wv_uu, Btvu);
  comb_w_t<<<256, blk, 0, stream>>>(W_kqv_drug, 0,   Wk_du, Btkd);
  comb_w_t<<<256, blk, 0, stream>>>(W_kqv_drug, 512, Wv_du, Btvd);
  comb_b<<<1, blk, 0, stream>>>(b_kqv_user, 0,   Wk_uu, bku);
  comb_b<<<1, blk, 0, stream>>>(b_kqv_user, 512, Wv_uu, bvu);
  comb_b<<<1, blk, 0, stream>>>(b_kqv_drug, 0,   Wk_du, bkd);
  comb_b<<<1, blk, 0, stream>>>(b_kqv_drug, 512, Wv_du, bvd);

  // ===== HAN branch =====
  hipMemsetAsync(s1a, 0, (size_t)NU * 8 * 4, stream);      // s1a+s1b
  hipMemsetAsync(o1, 0, (size_t)NU * 128 * 4, stream);     // o1+o2

  gemm_bf16<0><<<dim3(1, NUP / 128), blk, 0, stream>>>(
      xrb, Bth, b_han, h, 64, (unsigned short*)nullptr, 0, NU, 64, 128);

  han_alsd<<<g1((size_t)NU * 4), blk, 0, stream>>>(
      h, a_src_r1, a_dst_r1, a_src_r2, a_dst_r2, als1, ald1, als2, ald2);

  han_edge_exp<<<g1((size_t)NEDGE * 4), blk, 0, stream>>>(ei_r1, NEDGE, als1, ald1, ale, s1a);
  han_scatter <<<g1((size_t)NEDGE * 64), blk, 0, stream>>>(ei_r1, NEDGE, h, ale, s1a, o1);
  han_edge_exp<<<g1((size_t)NEDGE * 4), blk, 0, stream>>>(ei_r2, NEDGE, als2, ald2, ale, s1b);
  han_scatter <<<g1((size_t)NEDGE * 64), blk, 0, stream>>>(ei_r2, NEDGE, h, ale, s1b, o2);

  sem_colsum<<<dim3(nblocks_cs, 2), blk, 0, stream>>>(o1, o2, Wk_sem, bk_sem, colpart, nblocks_cs);
  sem_final<<<1, 128, 0, stream>>>(colpart, nblocks_cs, q_sem, semv);

  // ===== HGT GEMMs =====
  gemm_bf16<1><<<dim3(2, NUP / 128), blk, 0, stream>>>(
      xub, Btu_in, b_in_user, xu, 256, xub2, 256, NU, 256, 128);
  gemm_bf16<1><<<dim3(2, NDP / 128), blk, 0, stream>>>(
      xdb, Btd_in, b_in_drug, (float*)nullptr, 0, xdb2, 256, ND, 256, 128);

  gemm_bf16<0><<<dim3(2, NUP / 128), blk, 0, stream>>>(
      xub2, Btq,  b_kqv_user + 256, (float*)nullptr, 0, qub,  256, NU, 256, 256);
  gemm_bf16<0><<<dim3(2, NUP / 128), blk, 0, stream>>>(
      xub2, Btku, bku, (float*)nullptr, 0, kpub, 256, NU, 256, 256);
  gemm_bf16<0><<<dim3(2, NUP / 128), blk, 0, stream>>>(
      xub2, Btvu, bvu, (float*)nullptr, 0, vpub, 256, NU, 256, 256);
  gemm_bf16<0><<<dim3(2, NDP / 128), blk, 0, stream>>>(
      xdb2, Btkd, bkd, (float*)nullptr, 0, kpdb, 256, ND, 256, 256);
  gemm_bf16<0><<<dim3(2, NDP / 128), blk, 0, stream>>>(
      xdb2, Btvd, bvd, (float*)nullptr, 0, vpdb, 256, ND, 256, 256);

  // ===== HGT attention =====
  hipMemsetAsync(s2, 0, (size_t)NU * 4 * 4, stream);
  hgt_edge_exp<<<g1((size_t)NEDGE * 4), blk, 0, stream>>>(ei_du, NEDGE, qub, kpdb, p_du, ae_du, s2);
  hgt_edge_exp<<<g1((size_t)NEDGE * 4), blk, 0, stream>>>(ei_uu, NEDGE, qub, kpub, p_uu, ae_uu, s2);

  hipMemsetAsync(hout, 0, (size_t)NU * 256 * 4, stream);  // aliases qub+kpub (dead now)
  hgt_scatter<<<g1((size_t)NEDGE * 256), blk, 0, stream>>>(ei_du, NEDGE, vpdb, ae_du, s2, hout);
  hgt_scatter<<<g1((size_t)NEDGE * 256), blk, 0, stream>>>(ei_uu, NEDGE, vpub, ae_uu, s2, hout);

  gelu_conv<<<g1((size_t)NUP * 256), blk, 0, stream>>>(hout, houtb, NUP * 256);

  gemm_bf16<0><<<dim3(2, NUP / 128), blk, 0, stream>>>(
      houtb, Bto, b_out_user, afin, 320, (unsigned short*)nullptr, 0, NU, 256, 256);

  hipMemsetAsync(afinb + (size_t)NU * 320, 0, (size_t)(NUP - NU) * 320 * 2, stream);
  fill_ref_b<<<g1((size_t)NU * 64), blk, 0, stream>>>(o1, o2, semv, afinb);
  skip_mix_b<<<g1((size_t)NU * 256), blk, 0, stream>>>(afin, xu, skip_user, afinb);

  gemm_bf16<0><<<dim3(2, NUP / 128), blk, 0, stream>>>(
      afinb, Btf, b_fin, out, 256, (unsigned short*)nullptr, 0, NU, 256, 320);
}

// Round 3
// 618.336 us; speedup vs baseline: 2.3102x; 1.2170x over previous
//
#include <hip/hip_runtime.h>
#include <hip/hip_bf16.h>

#define NU 40000
#define ND 20000
#define NUP 40064   // 313*128
#define NDP 20096   // 157*128
#define FINC 128
#define HIDC 256
#define NHEAD 4
#define HANOUT 64
#define NEDGE 80000

typedef __attribute__((ext_vector_type(8))) short bf16x8;
typedef __attribute__((ext_vector_type(4))) float f32x4;

static __device__ __forceinline__ float b2f(unsigned short u) {
  union { unsigned int u; float f; } x; x.u = (unsigned int)u << 16; return x.f;
}
static __device__ __forceinline__ unsigned short f2b(float f) {
  union { float f; unsigned int u; } x; x.f = f;
  unsigned int r = x.u + 0x7FFFu + ((x.u >> 16) & 1u);
  return (unsigned short)(r >> 16);
}

static __device__ __forceinline__ void gload_lds16(const void* g, void* l) {
  __builtin_amdgcn_global_load_lds((const __attribute__((address_space(1))) unsigned int*)g,
                                   (__attribute__((address_space(3))) unsigned int*)l, 16, 0, 0);
}

// ============ bf16 MFMA GEMM: C = act(A @ Bt^T + bias) ============
// A: [Mpad][K] bf16 (row-major, stride K). Bt: [Npad][K] bf16 (= B transposed).
// grid = (Npad/128, Mpad/128), 256 threads (4 waves, 2x2).
// ACT 0: none, 1: relu, 2: tanh + column-sum -> atomicAdd(Cf[col]) (sem path).
template<int ACT>
__global__ __launch_bounds__(256)
void gemm_bf16(const unsigned short* __restrict__ A,
               const unsigned short* __restrict__ Bt,
               const float* __restrict__ bias,
               float* __restrict__ Cf, int ldcf,
               unsigned short* __restrict__ Cb, int ldcb,
               int M, int N, int K)
{
  __shared__ __attribute__((aligned(128))) unsigned short lds[16384]; // A 8192 + B 8192
  unsigned short* ldsA = lds;
  unsigned short* ldsB = lds + 8192;

  const int tid  = threadIdx.x;
  const int lane = tid & 63, wv = tid >> 6;
  const int row0 = blockIdx.y * 128, col0 = blockIdx.x * 128;

  const int rS = wv * 32 + (lane >> 3);
  const int sS = (lane & 7) ^ (lane >> 3);          // pre-swizzled source slot

  const int lr = lane & 15, lk = lane >> 4;
  const int wr = wv >> 1, wc = wv & 1;
  const int swz = lr & 7;

  f32x4 acc[4][4] = {};

  for (int k0 = 0; k0 < K; k0 += 64) {
#pragma unroll
    for (int i = 0; i < 4; i++) {
      size_t ga = (size_t)(row0 + rS + i * 8) * K + k0 + sS * 8;
      gload_lds16(A + ga, ldsA + wv * 2048 + i * 512);
      size_t gb = (size_t)(col0 + rS + i * 8) * K + k0 + sS * 8;
      gload_lds16(Bt + gb, ldsB + wv * 2048 + i * 512);
    }
    __syncthreads();
#pragma unroll
    for (int half = 0; half < 2; half++) {
      const int k8 = half * 4 + lk;
      const int so = (k8 ^ swz) << 3;
      bf16x8 av[4], bv[4];
#pragma unroll
      for (int m = 0; m < 4; m++)
        av[m] = *(const bf16x8*)&ldsA[(wr * 64 + m * 16 + lr) * 64 + so];
#pragma unroll
      for (int n = 0; n < 4; n++)
        bv[n] = *(const bf16x8*)&ldsB[(wc * 64 + n * 16 + lr) * 64 + so];
#pragma unroll
      for (int m = 0; m < 4; m++)
#pragma unroll
        for (int n = 0; n < 4; n++)
          acc[m][n] = __builtin_amdgcn_mfma_f32_16x16x32_bf16(av[m], bv[n], acc[m][n], 0, 0, 0);
    }
    __syncthreads();
  }

  if (ACT == 2) {
    // tanh + column-sum epilogue (sem path). N <= 64 assumed here.
    __shared__ float csum[64];
    if (tid < 64) csum[tid] = 0.f;
    __syncthreads();
#pragma unroll
    for (int n = 0; n < 4; n++) {
      int col = col0 + wc * 64 + n * 16 + lr;
      if (col < N) {
        float bi = bias[col];
        float local = 0.f;
#pragma unroll
        for (int m = 0; m < 4; m++)
#pragma unroll
          for (int g = 0; g < 4; g++) {
            int row = row0 + wr * 64 + m * 16 + lk * 4 + g;
            if (row < M) local += tanhf(acc[m][n][g] + bi);
          }
        atomicAdd(&csum[col], local);
      }
    }
    __syncthreads();
    if (tid < 64) atomicAdd(&Cf[tid], csum[tid]);
    return;
  }

#pragma unroll
  for (int n = 0; n < 4; n++) {
    int col = col0 + wc * 64 + n * 16 + lr;
    bool cok = col < N;
    float bi = cok ? bias[col] : 0.f;
#pragma unroll
    for (int m = 0; m < 4; m++) {
#pragma unroll
      for (int g = 0; g < 4; g++) {
        int row = row0 + wr * 64 + m * 16 + lk * 4 + g;
        float v = acc[m][n][g] + bi;
        if (ACT == 1) v = fmaxf(v, 0.f);
        if (cok) {
          if (Cf && row < M) Cf[(size_t)row * ldcf + col] = v;
          if (Cb) Cb[(size_t)row * ldcb + col] = f2b(row < M ? v : 0.f);
        }
      }
    }
  }
}

// ============ prep kernels ============
// f32 [M][C] -> bf16 [Mpad][C], zero pad rows; optional relu
__global__ void conv_pad(const float* __restrict__ in, unsigned short* __restrict__ out,
                         int M, int C, int total, int relu)
{
  int t = blockIdx.x * 256 + threadIdx.x;
  if (t >= total) return;
  int r = t / C;
  float v = (r < M) ? in[t] : 0.f;
  if (relu) v = fmaxf(v, 0.f);
  out[t] = f2b(v);
}

// W [K][N] (stride ldw, col offset) -> Bt bf16 [Npad][K], zero pad
__global__ void transp_conv(const float* __restrict__ W, int ldw, int coloff,
                            unsigned short* __restrict__ Bt, int K, int N, int total)
{
  int t = blockIdx.x * 256 + threadIdx.x;
  if (t >= total) return;
  int n = t / K, k = t - n * K;
  Bt[t] = (n < N) ? f2b(W[(size_t)k * ldw + coloff + n]) : 0;
}

// folded per-head weight, transposed bf16
__global__ void comb_w_t(const float* __restrict__ Wkqv, int coloff,
                         const float* __restrict__ Wh, unsigned short* __restrict__ Bt)
{
  int t = blockIdx.x * 256 + threadIdx.x;  // n*256 + c
  int n = t >> 8, c = t & 255;
  int hh = n >> 6, e = n & 63;
  float acc = 0.f;
  for (int d = 0; d < 64; d++)
    acc += Wkqv[(size_t)c * 768 + coloff + hh * 64 + d] * Wh[hh * 4096 + d * 64 + e];
  Bt[t] = f2b(acc);
}

__global__ void comb_b(const float* __restrict__ bkqv, int coloff,
                       const float* __restrict__ Wh, float* __restrict__ bout)
{
  int j = threadIdx.x;  // 256
  int hh = j >> 6, e = j & 63;
  float acc = 0.f;
  for (int d = 0; d < 64; d++)
    acc += bkqv[coloff + hh * 64 + d] * Wh[hh * 4096 + d * 64 + e];
  bout[j] = acc;
}

// ============ HAN ============
__global__ void han_alsd(const float* __restrict__ h,
                         const float* __restrict__ a_s1, const float* __restrict__ a_d1,
                         const float* __restrict__ a_s2, const float* __restrict__ a_d2,
                         float* __restrict__ als1, float* __restrict__ ald1,
                         float* __restrict__ als2, float* __restrict__ ald2)
{
  int t = blockIdx.x * 256 + threadIdx.x;
  if (t >= NU * NHEAD) return;
  int n = t >> 2, hh = t & 3;
  const float* hp = h + (size_t)n * 64 + hh * 16;
  float s1 = 0, d1 = 0, s2 = 0, d2 = 0;
#pragma unroll
  for (int d = 0; d < 16; d++) {
    float v = hp[d];
    s1 += v * a_s1[hh * 16 + d]; d1 += v * a_d1[hh * 16 + d];
    s2 += v * a_s2[hh * 16 + d]; d2 += v * a_d2[hh * 16 + d];
  }
  als1[t] = s1; ald1[t] = d1; als2[t] = s2; ald2[t] = d2;
}

__global__ void han_edge_exp(const int* __restrict__ ei, int ne,
                             const float* __restrict__ als, const float* __restrict__ ald,
                             float* __restrict__ ale, float* __restrict__ ssum)
{
  int t = blockIdx.x * 256 + threadIdx.x;
  if (t >= ne * NHEAD) return;
  int e = t >> 2, hh = t & 3;
  int s = ei[e], d = ei[ne + e];
  float al = als[s * 4 + hh] + ald[d * 4 + hh];
  al = (al >= 0.f) ? al : 0.2f * al;
  float ex = expf(al);
  ale[t] = ex;
  atomicAdd(&ssum[d * 4 + hh], ex);
}

__global__ void han_scatter(const int* __restrict__ ei, int ne,
                            const float* __restrict__ h,
                            const float* __restrict__ ale, const float* __restrict__ ssum,
                            float* __restrict__ o)
{
  int t = blockIdx.x * 256 + threadIdx.x;
  if (t >= ne * 64) return;
  int e = t >> 6, j = t & 63, hh = j >> 4;
  int s = ei[e], d = ei[ne + e];
  float w = ale[e * 4 + hh] / (ssum[d * 4 + hh] + 1e-16f);
  atomicAdd(&o[(size_t)d * 64 + j], h[(size_t)s * 64 + j] * w);
}

__global__ void sem_final2(const float* __restrict__ colpart2,
                           const float* __restrict__ q_sem, float* __restrict__ semv)
{
  int t = threadIdx.x;            // 128
  int j = t & 63;
  __shared__ float sv[128];
  sv[t] = colpart2[t] * q_sem[j] * (1.0f / NU);
  __syncthreads();
  if (t == 0) {
    float s0 = 0, s1 = 0;
    for (int i = 0; i < 64; i++) { s0 += sv[i]; s1 += sv[64 + i]; }
    float m = fmaxf(s0, s1);
    float e0 = expf(s0 - m), e1 = expf(s1 - m);
    semv[0] = e0 / (e0 + e1); semv[1] = e1 / (e0 + e1);
  }
}

// ============ HGT edge kernels (bf16 inputs) ============
__global__ void hgt_edge_exp(const int* __restrict__ ei, int ne,
                             const unsigned short* __restrict__ q,
                             const unsigned short* __restrict__ kp,
                             const float* __restrict__ p,
                             float* __restrict__ ae, float* __restrict__ ssum)
{
  int t = blockIdx.x * 256 + threadIdx.x;
  if (t >= ne * NHEAD) return;
  int e = t >> 2, hh = t & 3;
  int s = ei[e], d = ei[ne + e];
  const uint4* qv = (const uint4*)(q + (size_t)d * HIDC + hh * 64);
  const uint4* kv = (const uint4*)(kp + (size_t)s * HIDC + hh * 64);
  float acc = 0.f;
#pragma unroll
  for (int i = 0; i < 8; i++) {
    uint4 a = qv[i], b = kv[i];
    unsigned int aw[4] = {a.x, a.y, a.z, a.w};
    unsigned int bw[4] = {b.x, b.y, b.z, b.w};
#pragma unroll
    for (int u = 0; u < 4; u++) {
      acc += b2f((unsigned short)(aw[u] & 0xffff)) * b2f((unsigned short)(bw[u] & 0xffff));
      acc += b2f((unsigned short)(aw[u] >> 16))    * b2f((unsigned short)(bw[u] >> 16));
    }
  }
  float ex = expf(acc * p[hh] * 0.125f);
  ae[t] = ex;
  atomicAdd(&ssum[d * 4 + hh], ex);
}

__global__ void hgt_scatter(const int* __restrict__ ei, int ne,
                            const unsigned short* __restrict__ vp,
                            const float* __restrict__ ae, const float* __restrict__ ssum,
                            float* __restrict__ out)
{
  int t = blockIdx.x * 256 + threadIdx.x;
  if (t >= ne * HIDC) return;
  int e = t >> 8, j = t & 255, hh = j >> 6;
  int s = ei[e], d = ei[ne + e];
  float w = ae[e * 4 + hh] / (ssum[d * 4 + hh] + 1e-16f);
  atomicAdd(&out[(size_t)d * HIDC + j], b2f(vp[(size_t)s * HIDC + j]) * w);
}

// ============ epilogues ============
__global__ void gelu_conv(const float* __restrict__ in, unsigned short* __restrict__ outb,
                          int total)
{
  int t = blockIdx.x * 256 + threadIdx.x;
  if (t >= total) return;
  int r = t >> 8;
  float v = 0.f;
  if (r < NU) {
    float x = in[t];
    v = 0.5f * x * (1.f + erff(x * 0.70710678118654752f));
  }
  outb[t] = f2b(v);
}

__global__ void fill_ref_b(const float* __restrict__ o1, const float* __restrict__ o2,
                           const float* __restrict__ semv, unsigned short* __restrict__ afinb)
{
  int t = blockIdx.x * 256 + threadIdx.x;  // n*64 + j
  if (t >= NU * 64) return;
  int n = t >> 6, j = t & 63;
  float v = semv[0] * fmaxf(o1[t], 0.f) + semv[1] * fmaxf(o2[t], 0.f);
  afinb[(size_t)n * 320 + 256 + j] = f2b(v);
}

__global__ void skip_mix_b(const float* __restrict__ afin, const float* __restrict__ xu,
                           const float* __restrict__ skipp, unsigned short* __restrict__ afinb)
{
  int t = blockIdx.x * 256 + threadIdx.x;  // n*256 + j
  if (t >= NU * HIDC) return;
  int n = t >> 8, j = t & 255;
  float su = 1.f / (1.f + expf(-skipp[0]));
  float v = su * afin[(size_t)n * 320 + j] + (1.f - su) * xu[t];
  afinb[(size_t)n * 320 + j] = f2b(v);
}

// ------------------------------------------------------------------
extern "C" void kernel_launch(void* const* d_in, const int* in_sizes, int n_in,
                              void* d_out, int out_size, void* d_ws, size_t ws_size,
                              hipStream_t stream)
{
  (void)in_sizes; (void)n_in; (void)out_size; (void)ws_size;
  const float* x_user     = (const float*)d_in[0];
  const float* x_drug     = (const float*)d_in[1];
  const float* x_user_ref = (const float*)d_in[2];
  const int*   ei_du      = (const int*)d_in[4];
  const int*   ei_uu      = (const int*)d_in[5];
  const int*   ei_r1      = (const int*)d_in[6];
  const int*   ei_r2      = (const int*)d_in[7];
  const float* W_han      = (const float*)d_in[8];
  const float* b_han      = (const float*)d_in[9];
  const float* a_src_r1   = (const float*)d_in[10];
  const float* a_dst_r1   = (const float*)d_in[11];
  const float* a_src_r2   = (const float*)d_in[12];
  const float* a_dst_r2   = (const float*)d_in[13];
  const float* Wk_sem     = (const float*)d_in[14];
  const float* bk_sem     = (const float*)d_in[15];
  const float* q_sem      = (const float*)d_in[16];
  const float* W_in_user  = (const float*)d_in[17];
  const float* b_in_user  = (const float*)d_in[18];
  const float* W_in_drug  = (const float*)d_in[19];
  const float* b_in_drug  = (const float*)d_in[20];
  const float* W_kqv_user = (const float*)d_in[21];
  const float* b_kqv_user = (const float*)d_in[22];
  const float* W_kqv_drug = (const float*)d_in[23];
  const float* b_kqv_drug = (const float*)d_in[24];
  const float* Wk_du      = (const float*)d_in[28];
  const float* Wv_du      = (const float*)d_in[29];
  const float* p_du       = (const float*)d_in[30];
  const float* Wk_uu      = (const float*)d_in[31];
  const float* Wv_uu      = (const float*)d_in[32];
  const float* p_uu       = (const float*)d_in[33];
  const float* W_out_user = (const float*)d_in[34];
  const float* b_out_user = (const float*)d_in[35];
  const float* skip_user  = (const float*)d_in[38];
  const float* W_fin      = (const float*)d_in[40];
  const float* b_fin      = (const float*)d_in[41];
  float* out = (float*)d_out;

  // ---------------- workspace layout (bytes) ----------------
  char* base = (char*)d_ws;
  size_t off = 0;
  auto alloc = [&](size_t bytes) { char* p = base + off; off += (bytes + 255) & ~(size_t)255; return p; };

  float* h       = (float*)alloc((size_t)NU * 64 * 4);
  float* als1    = (float*)alloc((size_t)NU * 4 * 4);
  float* ald1    = (float*)alloc((size_t)NU * 4 * 4);
  float* als2    = (float*)alloc((size_t)NU * 4 * 4);
  float* ald2    = (float*)alloc((size_t)NU * 4 * 4);
  float* s1a     = (float*)alloc((size_t)NU * 4 * 4);
  float* s1b     = (float*)alloc((size_t)NU * 4 * 4);
  float* ale     = (float*)alloc((size_t)NEDGE * 4 * 4);
  float* o1      = (float*)alloc((size_t)NU * 64 * 4);
  float* o2      = (float*)alloc((size_t)NU * 64 * 4);
  float* colpart2= (float*)alloc(128 * 4);
  float* semv    = (float*)alloc(64);
  float* bku     = (float*)alloc(1024);
  float* bvu     = (float*)alloc(1024);
  float* bkd     = (float*)alloc(1024);
  float* bvd     = (float*)alloc(1024);
  float* xu      = (float*)alloc((size_t)NU * 256 * 4);
  float* ae_du   = (float*)alloc((size_t)NEDGE * 4 * 4);
  float* ae_uu   = (float*)alloc((size_t)NEDGE * 4 * 4);
  float* s2      = (float*)alloc((size_t)NU * 4 * 4);

  // region P: bf16 projections; later aliased by hout (f32)
  unsigned short* qub  = (unsigned short*)alloc((size_t)NUP * 256 * 2);
  unsigned short* kpub = (unsigned short*)alloc((size_t)NUP * 256 * 2);
  unsigned short* vpub = (unsigned short*)alloc((size_t)NUP * 256 * 2);
  unsigned short* kpdb = (unsigned short*)alloc((size_t)NDP * 256 * 2);
  unsigned short* vpdb = (unsigned short*)alloc((size_t)NDP * 256 * 2);
  float* hout = (float*)qub;  // aliases qub+kpub; written after edge_exp reads

  // region F: afin f32; earlier aliased by obf1/obf2 (sem, HAN phase) then xub2/xdb2
  float* afin = (float*)alloc((size_t)NU * 320 * 4);
  unsigned short* obf1 = (unsigned short*)afin;                       // [NUP][64]
  unsigned short* obf2 = (unsigned short*)afin + (size_t)NUP * 64;    // [NUP][64]
  unsigned short* xub2 = (unsigned short*)afin;
  unsigned short* xdb2 = (unsigned short*)afin + (size_t)NUP * 256;

  // region H: houtb bf16; earlier aliased by xrb
  unsigned short* houtb = (unsigned short*)alloc((size_t)NUP * 256 * 2);
  unsigned short* xrb   = houtb;

  // region AB: afinb bf16; earlier aliased by xub/xdb
  unsigned short* afinb = (unsigned short*)alloc((size_t)NUP * 320 * 2);
  unsigned short* xub   = afinb;
  unsigned short* xdb   = afinb + (size_t)NUP * 128;

  // weights (bf16, transposed)
  unsigned short* Btu_in = (unsigned short*)alloc(256 * 128 * 2);
  unsigned short* Btd_in = (unsigned short*)alloc(256 * 128 * 2);
  unsigned short* Btq    = (unsigned short*)alloc(256 * 256 * 2);
  unsigned short* Btku   = (unsigned short*)alloc(256 * 256 * 2);
  unsigned short* Btvu   = (unsigned short*)alloc(256 * 256 * 2);
  unsigned short* Btkd   = (unsigned short*)alloc(256 * 256 * 2);
  unsigned short* Btvd   = (unsigned short*)alloc(256 * 256 * 2);
  unsigned short* Bto    = (unsigned short*)alloc(256 * 256 * 2);
  unsigned short* Btf    = (unsigned short*)alloc(256 * 320 * 2);
  unsigned short* Bth    = (unsigned short*)alloc(128 * 128 * 2);
  unsigned short* BtWk   = (unsigned short*)alloc(128 * 64 * 2);

  const int B = 256;
  dim3 blk(B);
  auto g1 = [](size_t n) { return dim3((unsigned)((n + 255) / 256)); };

  // ===== prep: converts + weight transforms =====
  conv_pad<<<g1((size_t)NUP * 128), blk, 0, stream>>>(x_user, xub, NU, 128, NUP * 128, 0);
  conv_pad<<<g1((size_t)NDP * 128), blk, 0, stream>>>(x_drug, xdb, ND, 128, NDP * 128, 0);
  conv_pad<<<g1((size_t)NUP * 128), blk, 0, stream>>>(x_user_ref, xrb, NU, 128, NUP * 128, 0);

  transp_conv<<<g1(256 * 128), blk, 0, stream>>>(W_in_user, 256, 0, Btu_in, 128, 256, 256 * 128);
  transp_conv<<<g1(256 * 128), blk, 0, stream>>>(W_in_drug, 256, 0, Btd_in, 128, 256, 256 * 128);
  transp_conv<<<g1(256 * 256), blk, 0, stream>>>(W_kqv_user, 768, 256, Btq, 256, 256, 256 * 256);
  transp_conv<<<g1(256 * 256), blk, 0, stream>>>(W_out_user, 256, 0, Bto, 256, 256, 256 * 256);
  transp_conv<<<g1(256 * 320), blk, 0, stream>>>(W_fin, 256, 0, Btf, 320, 256, 256 * 320);
  transp_conv<<<g1(128 * 128), blk, 0, stream>>>(W_han, 64, 0, Bth, 128, 64, 128 * 128);
  transp_conv<<<g1(128 * 64), blk, 0, stream>>>(Wk_sem, 64, 0, BtWk, 64, 64, 128 * 64);

  comb_w_t<<<256, blk, 0, stream>>>(W_kqv_user, 0,   Wk_uu, Btku);
  comb_w_t<<<256, blk, 0, stream>>>(W_kqv_user, 512, Wv_uu, Btvu);
  comb_w_t<<<256, blk, 0, stream>>>(W_kqv_drug, 0,   Wk_du, Btkd);
  comb_w_t<<<256, blk, 0, stream>>>(W_kqv_drug, 512, Wv_du, Btvd);
  comb_b<<<1, blk, 0, stream>>>(b_kqv_user, 0,   Wk_uu, bku);
  comb_b<<<1, blk, 0, stream>>>(b_kqv_user, 512, Wv_uu, bvu);
  comb_b<<<1, blk, 0, stream>>>(b_kqv_drug, 0,   Wk_du, bkd);
  comb_b<<<1, blk, 0, stream>>>(b_kqv_drug, 512, Wv_du, bvd);

  // ===== HAN branch =====
  hipMemsetAsync(s1a, 0, (size_t)NU * 8 * 4, stream);      // s1a+s1b
  hipMemsetAsync(o1, 0, (size_t)NU * 128 * 4, stream);     // o1+o2
  hipMemsetAsync(colpart2, 0, 128 * 4, stream);

  gemm_bf16<0><<<dim3(1, NUP / 128), blk, 0, stream>>>(
      xrb, Bth, b_han, h, 64, (unsigned short*)nullptr, 0, NU, 64, 128);

  han_alsd<<<g1((size_t)NU * 4), blk, 0, stream>>>(
      h, a_src_r1, a_dst_r1, a_src_r2, a_dst_r2, als1, ald1, als2, ald2);

  han_edge_exp<<<g1((size_t)NEDGE * 4), blk, 0, stream>>>(ei_r1, NEDGE, als1, ald1, ale, s1a);
  han_scatter <<<g1((size_t)NEDGE * 64), blk, 0, stream>>>(ei_r1, NEDGE, h, ale, s1a, o1);
  han_edge_exp<<<g1((size_t)NEDGE * 4), blk, 0, stream>>>(ei_r2, NEDGE, als2, ald2, ale, s1b);
  han_scatter <<<g1((size_t)NEDGE * 64), blk, 0, stream>>>(ei_r2, NEDGE, h, ale, s1b, o2);

  // ===== semantic attention via MFMA (obf* alias afin region; dead before xub2) =====
  conv_pad<<<g1((size_t)NUP * 64), blk, 0, stream>>>(o1, obf1, NU, 64, NUP * 64, 1);
  conv_pad<<<g1((size_t)NUP * 64), blk, 0, stream>>>(o2, obf2, NU, 64, NUP * 64, 1);
  gemm_bf16<2><<<dim3(1, NUP / 128), blk, 0, stream>>>(
      obf1, BtWk, bk_sem, colpart2, 0, (unsigned short*)nullptr, 0, NU, 64, 64);
  gemm_bf16<2><<<dim3(1, NUP / 128), blk, 0, stream>>>(
      obf2, BtWk, bk_sem, colpart2 + 64, 0, (unsigned short*)nullptr, 0, NU, 64, 64);
  sem_final2<<<1, 128, 0, stream>>>(colpart2, q_sem, semv);

  // ===== HGT GEMMs =====
  gemm_bf16<1><<<dim3(2, NUP / 128), blk, 0, stream>>>(
      xub, Btu_in, b_in_user, xu, 256, xub2, 256, NU, 256, 128);
  gemm_bf16<1><<<dim3(2, NDP / 128), blk, 0, stream>>>(
      xdb, Btd_in, b_in_drug, (float*)nullptr, 0, xdb2, 256, ND, 256, 128);

  gemm_bf16<0><<<dim3(2, NUP / 128), blk, 0, stream>>>(
      xub2, Btq,  b_kqv_user + 256, (float*)nullptr, 0, qub,  256, NU, 256, 256);
  gemm_bf16<0><<<dim3(2, NUP / 128), blk, 0, stream>>>(
      xub2, Btku, bku, (float*)nullptr, 0, kpub, 256, NU, 256, 256);
  gemm_bf16<0><<<dim3(2, NUP / 128), blk, 0, stream>>>(
      xub2, Btvu, bvu, (float*)nullptr, 0, vpub, 256, NU, 256, 256);
  gemm_bf16<0><<<dim3(2, NDP / 128), blk, 0, stream>>>(
      xdb2, Btkd, bkd, (float*)nullptr, 0, kpdb, 256, ND, 256, 256);
  gemm_bf16<0><<<dim3(2, NDP / 128), blk, 0, stream>>>(
      xdb2, Btvd, bvd, (float*)nullptr, 0, vpdb, 256, ND, 256, 256);

  // ===== HGT attention =====
  hipMemsetAsync(s2, 0, (size_t)NU * 4 * 4, stream);
  hgt_edge_exp<<<g1((size_t)NEDGE * 4), blk, 0, stream>>>(ei_du, NEDGE, qub, kpdb, p_du, ae_du, s2);
  hgt_edge_exp<<<g1((size_t)NEDGE * 4), blk, 0, stream>>>(ei_uu, NEDGE, qub, kpub, p_uu, ae_uu, s2);

  hipMemsetAsync(hout, 0, (size_t)NU * 256 * 4, stream);  // aliases qub+kpub (dead now)
  hgt_scatter<<<g1((size_t)NEDGE * 256), blk, 0, stream>>>(ei_du, NEDGE, vpdb, ae_du, s2, hout);
  hgt_scatter<<<g1((size_t)NEDGE * 256), blk, 0, stream>>>(ei_uu, NEDGE, vpub, ae_uu, s2, hout);

  gelu_conv<<<g1((size_t)NUP * 256), blk, 0, stream>>>(hout, houtb, NUP * 256);

  gemm_bf16<0><<<dim3(2, NUP / 128), blk, 0, stream>>>(
      houtb, Bto, b_out_user, afin, 320, (unsigned short*)nullptr, 0, NU, 256, 256);

  hipMemsetAsync(afinb + (size_t)NU * 320, 0, (size_t)(NUP - NU) * 320 * 2, stream);
  fill_ref_b<<<g1((size_t)NU * 64), blk, 0, stream>>>(o1, o2, semv, afinb);
  skip_mix_b<<<g1((size_t)NU * 256), blk, 0, stream>>>(afin, xu, skip_user, afinb);

  gemm_bf16<0><<<dim3(2, NUP / 128), blk, 0, stream>>>(
      afinb, Btf, b_fin, out, 256, (unsigned short*)nullptr, 0, NU, 256, 320);
}

// Round 4
// 535.840 us; speedup vs baseline: 2.6659x; 1.1540x over previous
//
#include <hip/hip_runtime.h>
#include <hip/hip_bf16.h>

#define NU 40000
#define ND 20000
#define NUP 40064   // 313*128
#define NDP 20096   // 157*128
#define HIDC 256
#define NHEAD 4
#define NEDGE 80000

typedef __attribute__((ext_vector_type(8))) short bf16x8;
typedef __attribute__((ext_vector_type(4))) float f32x4;

static __device__ __forceinline__ float b2f(unsigned short u) {
  union { unsigned int u; float f; } x; x.u = (unsigned int)u << 16; return x.f;
}
static __device__ __forceinline__ unsigned short f2b(float f) {
  union { float f; unsigned int u; } x; x.f = f;
  unsigned int r = x.u + 0x7FFFu + ((x.u >> 16) & 1u);
  return (unsigned short)(r >> 16);
}

static __device__ __forceinline__ void gload_lds16(const void* g, void* l) {
  __builtin_amdgcn_global_load_lds((const __attribute__((address_space(1))) unsigned int*)g,
                                   (__attribute__((address_space(3))) unsigned int*)l, 16, 0, 0);
}

// ============ bf16 MFMA GEMM: C = act(A @ Bt^T + bias) ============
// A: [Mpad][K] bf16. Bt: [Npad][K] bf16. grid=(Npad/128, Mpad/128), 256 thr.
// ACT 0: none, 1: relu, 2: tanh+colsum->atomicAdd(Cf[col]),
// ACT 3: skip-mix epilogue: Cb = f2b(su*(acc+bias) + (1-su)*b2f(xprev)) (bf16)
template<int ACT>
__global__ __launch_bounds__(256)
void gemm_bf16(const unsigned short* __restrict__ A,
               const unsigned short* __restrict__ Bt,
               const float* __restrict__ bias,
               float* __restrict__ Cf, int ldcf,
               unsigned short* __restrict__ Cb, int ldcb,
               int M, int N, int K,
               const float* __restrict__ skipp,
               const unsigned short* __restrict__ xprev)
{
  __shared__ __attribute__((aligned(128))) unsigned short lds[16384];
  unsigned short* ldsA = lds;
  unsigned short* ldsB = lds + 8192;

  const int tid  = threadIdx.x;
  const int lane = tid & 63, wv = tid >> 6;
  const int row0 = blockIdx.y * 128, col0 = blockIdx.x * 128;

  const int rS = wv * 32 + (lane >> 3);
  const int sS = (lane & 7) ^ (lane >> 3);

  const int lr = lane & 15, lk = lane >> 4;
  const int wr = wv >> 1, wc = wv & 1;
  const int swz = lr & 7;

  f32x4 acc[4][4] = {};

  for (int k0 = 0; k0 < K; k0 += 64) {
#pragma unroll
    for (int i = 0; i < 4; i++) {
      size_t ga = (size_t)(row0 + rS + i * 8) * K + k0 + sS * 8;
      gload_lds16(A + ga, ldsA + wv * 2048 + i * 512);
      size_t gb = (size_t)(col0 + rS + i * 8) * K + k0 + sS * 8;
      gload_lds16(Bt + gb, ldsB + wv * 2048 + i * 512);
    }
    __syncthreads();
#pragma unroll
    for (int half = 0; half < 2; half++) {
      const int k8 = half * 4 + lk;
      const int so = (k8 ^ swz) << 3;
      bf16x8 av[4], bv[4];
#pragma unroll
      for (int m = 0; m < 4; m++)
        av[m] = *(const bf16x8*)&ldsA[(wr * 64 + m * 16 + lr) * 64 + so];
#pragma unroll
      for (int n = 0; n < 4; n++)
        bv[n] = *(const bf16x8*)&ldsB[(wc * 64 + n * 16 + lr) * 64 + so];
#pragma unroll
      for (int m = 0; m < 4; m++)
#pragma unroll
        for (int n = 0; n < 4; n++)
          acc[m][n] = __builtin_amdgcn_mfma_f32_16x16x32_bf16(av[m], bv[n], acc[m][n], 0, 0, 0);
    }
    __syncthreads();
  }

  if (ACT == 2) {
    __shared__ float csum[64];
    if (tid < 64) csum[tid] = 0.f;
    __syncthreads();
#pragma unroll
    for (int n = 0; n < 4; n++) {
      int col = col0 + wc * 64 + n * 16 + lr;
      if (col < N) {
        float bi = bias[col];
        float local = 0.f;
#pragma unroll
        for (int m = 0; m < 4; m++)
#pragma unroll
          for (int g = 0; g < 4; g++) {
            int row = row0 + wr * 64 + m * 16 + lk * 4 + g;
            if (row < M) local += tanhf(acc[m][n][g] + bi);
          }
        atomicAdd(&csum[col], local);
      }
    }
    __syncthreads();
    if (tid < 64) atomicAdd(&Cf[tid], csum[tid]);
    return;
  }

  if (ACT == 3) {
    float su = 1.f / (1.f + expf(-skipp[0]));
#pragma unroll
    for (int n = 0; n < 4; n++) {
      int col = col0 + wc * 64 + n * 16 + lr;
      float bi = bias[col];
#pragma unroll
      for (int m = 0; m < 4; m++)
#pragma unroll
        for (int g = 0; g < 4; g++) {
          int row = row0 + wr * 64 + m * 16 + lk * 4 + g;
          float v = 0.f;
          if (row < M)
            v = su * (acc[m][n][g] + bi) + (1.f - su) * b2f(xprev[(size_t)row * 256 + col]);
          Cb[(size_t)row * ldcb + col] = f2b(v);
        }
    }
    return;
  }

#pragma unroll
  for (int n = 0; n < 4; n++) {
    int col = col0 + wc * 64 + n * 16 + lr;
    bool cok = col < N;
    float bi = cok ? bias[col] : 0.f;
#pragma unroll
    for (int m = 0; m < 4; m++) {
#pragma unroll
      for (int g = 0; g < 4; g++) {
        int row = row0 + wr * 64 + m * 16 + lk * 4 + g;
        float v = acc[m][n][g] + bi;
        if (ACT == 1) v = fmaxf(v, 0.f);
        if (cok) {
          if (Cf && row < M) Cf[(size_t)row * ldcf + col] = v;
          if (Cb) Cb[(size_t)row * ldcb + col] = f2b(row < M ? v : 0.f);
        }
      }
    }
  }
}

// ============ prep kernels ============
__global__ void conv_pad(const float* __restrict__ in, unsigned short* __restrict__ out,
                         int M, int C, int total)
{
  int t = blockIdx.x * 256 + threadIdx.x;
  if (t >= total) return;
  int r = t / C;
  out[t] = (r < M) ? f2b(in[t]) : 0;
}

__global__ void transp_conv(const float* __restrict__ W, int ldw, int coloff,
                            unsigned short* __restrict__ Bt, int K, int N, int total)
{
  int t = blockIdx.x * 256 + threadIdx.x;
  if (t >= total) return;
  int n = t / K, k = t - n * K;
  Bt[t] = (n < N) ? f2b(W[(size_t)k * ldw + coloff + n]) : 0;
}

__global__ void comb_w_t(const float* __restrict__ Wkqv, int coloff,
                         const float* __restrict__ Wh, unsigned short* __restrict__ Bt)
{
  int t = blockIdx.x * 256 + threadIdx.x;  // n*256 + c
  int n = t >> 8, c = t & 255;
  int hh = n >> 6, e = n & 63;
  float acc = 0.f;
  for (int d = 0; d < 64; d++)
    acc += Wkqv[(size_t)c * 768 + coloff + hh * 64 + d] * Wh[hh * 4096 + d * 64 + e];
  Bt[t] = f2b(acc);
}

__global__ void comb_b(const float* __restrict__ bkqv, int coloff,
                       const float* __restrict__ Wh, float* __restrict__ bout)
{
  int j = threadIdx.x;
  int hh = j >> 6, e = j & 63;
  float acc = 0.f;
  for (int d = 0; d < 64; d++)
    acc += bkqv[coloff + hh * 64 + d] * Wh[hh * 4096 + d * 64 + e];
  bout[j] = acc;
}

__global__ void copy_f32(const float* __restrict__ src, float* __restrict__ dst, int n)
{
  int t = blockIdx.x * 256 + threadIdx.x;
  if (t < n) dst[t] = src[t];
}

// ============ CSR build ============
__global__ void hist_dst(const int* __restrict__ ei, int ne, int* __restrict__ cnt)
{
  int t = blockIdx.x * 256 + threadIdx.x;
  if (t < ne) atomicAdd(&cnt[ei[ne + t]], 1);
}

__global__ __launch_bounds__(256)
void scan3(const int* __restrict__ cnt, int* __restrict__ rs)
{
  const int y = blockIdx.x;
  const int* c = cnt + (size_t)y * NU;
  int* r = rs + (size_t)y * NUP;
  int t = threadIdx.x;
  const int CH = (NU + 255) / 256;  // 157
  int lo = t * CH, hi = min(lo + CH, NU);
  int s = 0;
  for (int i = lo; i < hi; i++) s += c[i];
  __shared__ int ps[256];
  ps[t] = s;
  __syncthreads();
  for (int d = 1; d < 256; d <<= 1) {
    int o = (t >= d) ? ps[t - d] : 0;
    __syncthreads();
    ps[t] += o;
    __syncthreads();
  }
  int run = ps[t] - s;   // exclusive
  for (int i = lo; i < hi; i++) { r[i] = run; run += c[i]; }
  if (t == 255) r[NU] = run;
}

// ============ HAN ============
__global__ void han_alsd(const float* __restrict__ h,
                         const float* __restrict__ a_s1, const float* __restrict__ a_d1,
                         const float* __restrict__ a_s2, const float* __restrict__ a_d2,
                         float* __restrict__ als1, float* __restrict__ ald1,
                         float* __restrict__ als2, float* __restrict__ ald2)
{
  int t = blockIdx.x * 256 + threadIdx.x;
  if (t >= NU * NHEAD) return;
  int n = t >> 2, hh = t & 3;
  const float* hp = h + (size_t)n * 64 + hh * 16;
  float s1 = 0, d1 = 0, s2 = 0, d2 = 0;
#pragma unroll
  for (int d = 0; d < 16; d++) {
    float v = hp[d];
    s1 += v * a_s1[hh * 16 + d]; d1 += v * a_d1[hh * 16 + d];
    s2 += v * a_s2[hh * 16 + d]; d2 += v * a_d2[hh * 16 + d];
  }
  als1[t] = s1; ald1[t] = d1; als2[t] = s2; ald2[t] = d2;
}

__global__ void han_fill(const int* __restrict__ ei, int ne,
                         const float* __restrict__ als, const float* __restrict__ ald,
                         const int* __restrict__ rs, int* __restrict__ cur,
                         int* __restrict__ esrc, float* __restrict__ aev)
{
  int t = blockIdx.x * 256 + threadIdx.x;
  if (t >= ne * 4) return;
  int e = t >> 2, hh = t & 3;
  int s = ei[e], d = ei[ne + e];
  float al = als[s * 4 + hh] + ald[d * 4 + hh];
  al = (al >= 0.f) ? al : 0.2f * al;
  float ex = expf(al);
  int pos = 0;
  if (hh == 0) pos = rs[d] + atomicAdd(&cur[d], 1);
  pos = __shfl(pos, 0, 4);
  aev[pos * 4 + hh] = ex;
  if (hh == 0) esrc[pos] = s;
}

// one wave per dst row; softmax denom in-register; writes relu'd bf16
__global__ __launch_bounds__(256)
void han_gather(const int* __restrict__ rs, const int* __restrict__ esrc,
                const float* __restrict__ aev, const float* __restrict__ h,
                unsigned short* __restrict__ obf)
{
  int gid = blockIdx.x * 256 + threadIdx.x;
  int wid = gid >> 6, lane = gid & 63;
  if (wid >= NUP) return;
  int head = lane >> 4;
  int beg = 0, end = 0;
  if (wid < NU) { beg = rs[wid]; end = rs[wid + 1]; }
  float asum = 0.f;
  for (int i = beg; i < end; i++) asum += aev[i * 4 + head];
  float inv = 1.f / (asum + 1e-16f);
  float a = 0.f;
  for (int i = beg; i < end; i++)
    a += aev[i * 4 + head] * inv * h[(size_t)esrc[i] * 64 + lane];
  obf[(size_t)wid * 64 + lane] = f2b(fmaxf(a, 0.f));
}

__global__ void sem_final2(const float* __restrict__ colpart2,
                           const float* __restrict__ q_sem, float* __restrict__ semv)
{
  int t = threadIdx.x;            // 128
  int j = t & 63;
  __shared__ float sv[128];
  sv[t] = colpart2[t] * q_sem[j] * (1.0f / NU);
  __syncthreads();
  if (t == 0) {
    float s0 = 0, s1 = 0;
    for (int i = 0; i < 64; i++) { s0 += sv[i]; s1 += sv[64 + i]; }
    float m = fmaxf(s0, s1);
    float e0 = expf(s0 - m), e1 = expf(s1 - m);
    semv[0] = e0 / (e0 + e1); semv[1] = e1 / (e0 + e1);
  }
}

// ============ HGT ============
// fill: per (edge,head) q.k dot + exp; slot via cursor; store v-row offset + exps
__global__ void hgt_fill(const int* __restrict__ ei, int ne,
                         const unsigned short* __restrict__ qb,
                         const unsigned short* __restrict__ kb, int ks, int voff,
                         const float* __restrict__ p,
                         const int* __restrict__ rs, int* __restrict__ cur,
                         int* __restrict__ esrc, float* __restrict__ aev)
{
  int t = blockIdx.x * 256 + threadIdx.x;
  if (t >= ne * 4) return;
  int e = t >> 2, hh = t & 3;
  int s = ei[e], d = ei[ne + e];
  const uint4* qv = (const uint4*)(qb + (size_t)d * 768 + 256 + hh * 64);
  const uint4* kv = (const uint4*)(kb + (size_t)s * ks + hh * 64);
  float acc = 0.f;
#pragma unroll
  for (int i = 0; i < 8; i++) {
    uint4 a = qv[i], b = kv[i];
    unsigned int aw[4] = {a.x, a.y, a.z, a.w};
    unsigned int bw[4] = {b.x, b.y, b.z, b.w};
#pragma unroll
    for (int u = 0; u < 4; u++) {
      acc += b2f((unsigned short)(aw[u] & 0xffff)) * b2f((unsigned short)(bw[u] & 0xffff));
      acc += b2f((unsigned short)(aw[u] >> 16))    * b2f((unsigned short)(bw[u] >> 16));
    }
  }
  float ex = expf(acc * p[hh] * 0.125f);
  int pos = 0;
  if (hh == 0) pos = rs[d] + atomicAdd(&cur[d], 1);
  pos = __shfl(pos, 0, 4);
  aev[pos * 4 + hh] = ex;
  if (hh == 0) esrc[pos] = voff + s * ks;
}

// one wave per dst row (256 cols, 4/lane); fused softmax + gelu + bf16 out
__global__ __launch_bounds__(256)
void hgt_gather(const int* __restrict__ rs, const int* __restrict__ esrc,
                const float* __restrict__ aev, const unsigned short* __restrict__ vbase,
                unsigned short* __restrict__ houtb)
{
  int gid = blockIdx.x * 256 + threadIdx.x;
  int wid = gid >> 6, lane = gid & 63;
  if (wid >= NUP) return;
  int head = lane >> 4;
  int beg = 0, end = 0;
  if (wid < NU) { beg = rs[wid]; end = rs[wid + 1]; }
  float asum = 0.f;
  for (int i = beg; i < end; i++) asum += aev[i * 4 + head];
  float inv = 1.f / (asum + 1e-16f);
  float a0 = 0, a1 = 0, a2 = 0, a3 = 0;
  for (int i = beg; i < end; i++) {
    float w = aev[i * 4 + head] * inv;
    const ushort4 v = *(const ushort4*)(vbase + (size_t)esrc[i] + lane * 4);
    a0 += b2f(v.x) * w; a1 += b2f(v.y) * w; a2 += b2f(v.z) * w; a3 += b2f(v.w) * w;
  }
  ushort4 o;
  o.x = f2b(0.5f * a0 * (1.f + erff(a0 * 0.70710678118654752f)));
  o.y = f2b(0.5f * a1 * (1.f + erff(a1 * 0.70710678118654752f)));
  o.z = f2b(0.5f * a2 * (1.f + erff(a2 * 0.70710678118654752f)));
  o.w = f2b(0.5f * a3 * (1.f + erff(a3 * 0.70710678118654752f)));
  *(ushort4*)(houtb + (size_t)wid * 256 + lane * 4) = o;
}

// ============ epilogues ============
__global__ void fill_ref_b(const unsigned short* __restrict__ obf1,
                           const unsigned short* __restrict__ obf2,
                           const float* __restrict__ semv, unsigned short* __restrict__ afinb)
{
  int t = blockIdx.x * 256 + threadIdx.x;  // n*64 + j
  if (t >= NU * 64) return;
  int n = t >> 6, j = t & 63;
  float v = semv[0] * b2f(obf1[t]) + semv[1] * b2f(obf2[t]);  // already relu'd
  afinb[(size_t)n * 320 + 256 + j] = f2b(v);
}

// ------------------------------------------------------------------
extern "C" void kernel_launch(void* const* d_in, const int* in_sizes, int n_in,
                              void* d_out, int out_size, void* d_ws, size_t ws_size,
                              hipStream_t stream)
{
  (void)in_sizes; (void)n_in; (void)out_size; (void)ws_size;
  const float* x_user     = (const float*)d_in[0];
  const float* x_drug     = (const float*)d_in[1];
  const float* x_user_ref = (const float*)d_in[2];
  const int*   ei_du      = (const int*)d_in[4];
  const int*   ei_uu      = (const int*)d_in[5];
  const int*   ei_r1      = (const int*)d_in[6];
  const int*   ei_r2      = (const int*)d_in[7];
  const float* W_han      = (const float*)d_in[8];
  const float* b_han      = (const float*)d_in[9];
  const float* a_src_r1   = (const float*)d_in[10];
  const float* a_dst_r1   = (const float*)d_in[11];
  const float* a_src_r2   = (const float*)d_in[12];
  const float* a_dst_r2   = (const float*)d_in[13];
  const float* Wk_sem     = (const float*)d_in[14];
  const float* bk_sem     = (const float*)d_in[15];
  const float* q_sem      = (const float*)d_in[16];
  const float* W_in_user  = (const float*)d_in[17];
  const float* b_in_user  = (const float*)d_in[18];
  const float* W_in_drug  = (const float*)d_in[19];
  const float* b_in_drug  = (const float*)d_in[20];
  const float* W_kqv_user = (const float*)d_in[21];
  const float* b_kqv_user = (const float*)d_in[22];
  const float* W_kqv_drug = (const float*)d_in[23];
  const float* b_kqv_drug = (const float*)d_in[24];
  const float* Wk_du      = (const float*)d_in[28];
  const float* Wv_du      = (const float*)d_in[29];
  const float* p_du       = (const float*)d_in[30];
  const float* Wk_uu      = (const float*)d_in[31];
  const float* Wv_uu      = (const float*)d_in[32];
  const float* p_uu       = (const float*)d_in[33];
  const float* W_out_user = (const float*)d_in[34];
  const float* b_out_user = (const float*)d_in[35];
  const float* skip_user  = (const float*)d_in[38];
  const float* W_fin      = (const float*)d_in[40];
  const float* b_fin      = (const float*)d_in[41];
  float* out = (float*)d_out;

  // ---------------- workspace ----------------
  char* base = (char*)d_ws;
  size_t off = 0;
  auto alloc = [&](size_t bytes) { char* p = base + off; off += (bytes + 255) & ~(size_t)255; return p; };

  float* h       = (float*)alloc((size_t)NU * 64 * 4);
  float* als1    = (float*)alloc((size_t)NU * 4 * 4);
  float* ald1    = (float*)alloc((size_t)NU * 4 * 4);
  float* als2    = (float*)alloc((size_t)NU * 4 * 4);
  float* ald2    = (float*)alloc((size_t)NU * 4 * 4);
  float* colpart2= (float*)alloc(128 * 4);
  float* semv    = (float*)alloc(64);
  float* ball_u  = (float*)alloc(768 * 4);
  float* ball_d  = (float*)alloc(512 * 4);

  // CSR arrays: cnt[3][NU], rs[3][NUP]
  int* cnt   = (int*)alloc((size_t)3 * NU * 4);
  int* rs    = (int*)alloc((size_t)3 * NUP * 4);
  int* esrcH = (int*)alloc((size_t)2 * NEDGE * 4);
  float* aevH= (float*)alloc((size_t)2 * NEDGE * 4 * 4);
  int* esrc1 = (int*)alloc((size_t)NEDGE * 4);
  float* aev1= (float*)alloc((size_t)NEDGE * 4 * 4);
  int* esrc2 = (int*)alloc((size_t)NEDGE * 4);
  float* aev2= (float*)alloc((size_t)NEDGE * 4 * 4);

  unsigned short* obf1 = (unsigned short*)alloc((size_t)NUP * 64 * 2);
  unsigned short* obf2 = (unsigned short*)alloc((size_t)NUP * 64 * 2);

  // qukvb [NUP][768] (k'|q|v') and kvdb [NDP][512] (k'|v') — contiguous pair
  unsigned short* qukvb = (unsigned short*)alloc((size_t)NUP * 768 * 2);
  unsigned short* kvdb  = (unsigned short*)alloc((size_t)NDP * 512 * 2);

  unsigned short* xub2d = (unsigned short*)alloc((size_t)NUP * 256 * 2);  // relu(in-gemm) user
  unsigned short* xdb2d = (unsigned short*)alloc((size_t)NDP * 256 * 2);  // relu(in-gemm) drug

  // houtb bf16; earlier aliased by xrb (dead after HAN h-gemm)
  unsigned short* houtb = (unsigned short*)alloc((size_t)NUP * 256 * 2);
  unsigned short* xrb   = houtb;

  // afinb bf16 [NUP][320]; earlier aliased by xub/xdb (dead after input gemms)
  unsigned short* afinb = (unsigned short*)alloc((size_t)NUP * 320 * 2);
  unsigned short* xub   = afinb;
  unsigned short* xdb   = afinb + (size_t)NUP * 128;

  // weights (bf16, transposed)
  unsigned short* Btu_in  = (unsigned short*)alloc(256 * 128 * 2);
  unsigned short* Btd_in  = (unsigned short*)alloc(256 * 128 * 2);
  unsigned short* Btall_u = (unsigned short*)alloc(768 * 256 * 2);
  unsigned short* Btall_d = (unsigned short*)alloc(512 * 256 * 2);
  unsigned short* Bto     = (unsigned short*)alloc(256 * 256 * 2);
  unsigned short* Btf     = (unsigned short*)alloc(256 * 320 * 2);
  unsigned short* Bth     = (unsigned short*)alloc(128 * 128 * 2);
  unsigned short* BtWk    = (unsigned short*)alloc(128 * 64 * 2);

  const int B = 256;
  dim3 blk(B);
  auto g1 = [](size_t n) { return dim3((unsigned)((n + 255) / 256)); };

  // ===== prep: converts + weight transforms =====
  conv_pad<<<g1((size_t)NUP * 128), blk, 0, stream>>>(x_user, xub, NU, 128, NUP * 128);
  conv_pad<<<g1((size_t)NDP * 128), blk, 0, stream>>>(x_drug, xdb, ND, 128, NDP * 128);
  conv_pad<<<g1((size_t)NUP * 128), blk, 0, stream>>>(x_user_ref, xrb, NU, 128, NUP * 128);

  transp_conv<<<g1(256 * 128), blk, 0, stream>>>(W_in_user, 256, 0, Btu_in, 128, 256, 256 * 128);
  transp_conv<<<g1(256 * 128), blk, 0, stream>>>(W_in_drug, 256, 0, Btd_in, 128, 256, 256 * 128);
  transp_conv<<<g1(256 * 256), blk, 0, stream>>>(W_kqv_user, 768, 256, Btall_u + 256 * 256, 256, 256, 256 * 256);
  transp_conv<<<g1(256 * 256), blk, 0, stream>>>(W_out_user, 256, 0, Bto, 256, 256, 256 * 256);
  transp_conv<<<g1(256 * 320), blk, 0, stream>>>(W_fin, 256, 0, Btf, 320, 256, 256 * 320);
  transp_conv<<<g1(128 * 128), blk, 0, stream>>>(W_han, 64, 0, Bth, 128, 64, 128 * 128);
  transp_conv<<<g1(128 * 64), blk, 0, stream>>>(Wk_sem, 64, 0, BtWk, 64, 64, 128 * 64);

  comb_w_t<<<256, blk, 0, stream>>>(W_kqv_user, 0,   Wk_uu, Btall_u);
  comb_w_t<<<256, blk, 0, stream>>>(W_kqv_user, 512, Wv_uu, Btall_u + 512 * 256);
  comb_w_t<<<256, blk, 0, stream>>>(W_kqv_drug, 0,   Wk_du, Btall_d);
  comb_w_t<<<256, blk, 0, stream>>>(W_kqv_drug, 512, Wv_du, Btall_d + 256 * 256);
  comb_b<<<1, blk, 0, stream>>>(b_kqv_user, 0,   Wk_uu, ball_u);
  copy_f32<<<1, blk, 0, stream>>>(b_kqv_user + 256, ball_u + 256, 256);
  comb_b<<<1, blk, 0, stream>>>(b_kqv_user, 512, Wv_uu, ball_u + 512);
  comb_b<<<1, blk, 0, stream>>>(b_kqv_drug, 0,   Wk_du, ball_d);
  comb_b<<<1, blk, 0, stream>>>(b_kqv_drug, 512, Wv_du, ball_d + 256);

  // ===== CSR build (depends only on edge lists) =====
  hipMemsetAsync(cnt, 0, (size_t)3 * NU * 4, stream);
  hist_dst<<<g1(NEDGE), blk, 0, stream>>>(ei_du, NEDGE, cnt);
  hist_dst<<<g1(NEDGE), blk, 0, stream>>>(ei_uu, NEDGE, cnt);
  hist_dst<<<g1(NEDGE), blk, 0, stream>>>(ei_r1, NEDGE, cnt + NU);
  hist_dst<<<g1(NEDGE), blk, 0, stream>>>(ei_r2, NEDGE, cnt + 2 * NU);
  scan3<<<3, blk, 0, stream>>>(cnt, rs);
  hipMemsetAsync(cnt, 0, (size_t)3 * NU * 4, stream);   // reuse as cursors
  hipMemsetAsync(colpart2, 0, 128 * 4, stream);

  // ===== HAN branch =====
  gemm_bf16<0><<<dim3(1, NUP / 128), blk, 0, stream>>>(
      xrb, Bth, b_han, h, 64, (unsigned short*)nullptr, 0, NU, 64, 128, nullptr, nullptr);

  han_alsd<<<g1((size_t)NU * 4), blk, 0, stream>>>(
      h, a_src_r1, a_dst_r1, a_src_r2, a_dst_r2, als1, ald1, als2, ald2);

  han_fill<<<g1((size_t)NEDGE * 4), blk, 0, stream>>>(ei_r1, NEDGE, als1, ald1,
      rs + NUP, cnt + NU, esrc1, aev1);
  han_fill<<<g1((size_t)NEDGE * 4), blk, 0, stream>>>(ei_r2, NEDGE, als2, ald2,
      rs + 2 * NUP, cnt + 2 * NU, esrc2, aev2);
  han_gather<<<g1((size_t)NUP * 64), blk, 0, stream>>>(rs + NUP, esrc1, aev1, h, obf1);
  han_gather<<<g1((size_t)NUP * 64), blk, 0, stream>>>(rs + 2 * NUP, esrc2, aev2, h, obf2);

  gemm_bf16<2><<<dim3(1, NUP / 128), blk, 0, stream>>>(
      obf1, BtWk, bk_sem, colpart2, 0, (unsigned short*)nullptr, 0, NU, 64, 64, nullptr, nullptr);
  gemm_bf16<2><<<dim3(1, NUP / 128), blk, 0, stream>>>(
      obf2, BtWk, bk_sem, colpart2 + 64, 0, (unsigned short*)nullptr, 0, NU, 64, 64, nullptr, nullptr);
  sem_final2<<<1, 128, 0, stream>>>(colpart2, q_sem, semv);

  // ===== HGT GEMMs =====
  gemm_bf16<1><<<dim3(2, NUP / 128), blk, 0, stream>>>(
      xub, Btu_in, b_in_user, (float*)nullptr, 0, xub2d, 256, NU, 256, 128, nullptr, nullptr);
  gemm_bf16<1><<<dim3(2, NDP / 128), blk, 0, stream>>>(
      xdb, Btd_in, b_in_drug, (float*)nullptr, 0, xdb2d, 256, ND, 256, 128, nullptr, nullptr);

  gemm_bf16<0><<<dim3(6, NUP / 128), blk, 0, stream>>>(
      xub2d, Btall_u, ball_u, (float*)nullptr, 0, qukvb, 768, NU, 768, 256, nullptr, nullptr);
  gemm_bf16<0><<<dim3(4, NDP / 128), blk, 0, stream>>>(
      xdb2d, Btall_d, ball_d, (float*)nullptr, 0, kvdb, 512, ND, 512, 256, nullptr, nullptr);

  // ===== HGT attention: fill (q.k + exp) then gather (softmax+PV+gelu) =====
  hgt_fill<<<g1((size_t)NEDGE * 4), blk, 0, stream>>>(ei_du, NEDGE,
      qukvb, kvdb, 512, NUP * 768 + 256, p_du, rs, cnt, esrcH, aevH);
  hgt_fill<<<g1((size_t)NEDGE * 4), blk, 0, stream>>>(ei_uu, NEDGE,
      qukvb, qukvb, 768, 512, p_uu, rs, cnt, esrcH, aevH);
  hgt_gather<<<g1((size_t)NUP * 64), blk, 0, stream>>>(rs, esrcH, aevH, qukvb, houtb);

  // ===== output head =====
  hipMemsetAsync(afinb + (size_t)NU * 320, 0, (size_t)(NUP - NU) * 320 * 2, stream);
  gemm_bf16<3><<<dim3(2, NUP / 128), blk, 0, stream>>>(
      houtb, Bto, b_out_user, (float*)nullptr, 0, afinb, 320, NU, 256, 256, skip_user, xub2d);
  fill_ref_b<<<g1((size_t)NU * 64), blk, 0, stream>>>(obf1, obf2, semv, afinb);

  gemm_bf16<0><<<dim3(2, NUP / 128), blk, 0, stream>>>(
      afinb, Btf, b_fin, out, 256, (unsigned short*)nullptr, 0, NU, 256, 320, nullptr, nullptr);
}

// Round 5
// 477.856 us; speedup vs baseline: 2.9894x; 1.1213x over previous
//
#include <hip/hip_runtime.h>
#include <hip/hip_bf16.h>

#define NU 40000
#define ND 20000
#define NUP 40064   // 313*128
#define NDP 20096   // 157*128
#define HIDC 256
#define NHEAD 4
#define NEDGE 80000
#define CHUNK 2048
#define NCH 20      // ceil(NU/CHUNK)

typedef __attribute__((ext_vector_type(8))) short bf16x8;
typedef __attribute__((ext_vector_type(4))) float f32x4;

static __device__ __forceinline__ float b2f(unsigned short u) {
  union { unsigned int u; float f; } x; x.u = (unsigned int)u << 16; return x.f;
}
static __device__ __forceinline__ unsigned short f2b(float f) {
  union { float f; unsigned int u; } x; x.f = f;
  unsigned int r = x.u + 0x7FFFu + ((x.u >> 16) & 1u);
  return (unsigned short)(r >> 16);
}

static __device__ __forceinline__ void gload_lds16(const void* g, void* l) {
  __builtin_amdgcn_global_load_lds((const __attribute__((address_space(1))) unsigned int*)g,
                                   (__attribute__((address_space(3))) unsigned int*)l, 16, 0, 0);
}

// ============ bf16 MFMA GEMM: C = act(A @ Bt^T + bias) ============
// A: [Mpad][K] bf16. Bt: [Npad][K] bf16. grid=(Npad/128, Mpad/128), 256 thr.
// ACT 0: none, 1: relu, 2: tanh+colsum->atomicAdd(Cf[col]),
// ACT 3: skip-mix epilogue: Cb = f2b(su*(acc+bias) + (1-su)*b2f(xprev)) (bf16)
template<int ACT>
__global__ __launch_bounds__(256)
void gemm_bf16(const unsigned short* __restrict__ A,
               const unsigned short* __restrict__ Bt,
               const float* __restrict__ bias,
               float* __restrict__ Cf, int ldcf,
               unsigned short* __restrict__ Cb, int ldcb,
               int M, int N, int K,
               const float* __restrict__ skipp,
               const unsigned short* __restrict__ xprev)
{
  __shared__ __attribute__((aligned(128))) unsigned short lds[16384];
  unsigned short* ldsA = lds;
  unsigned short* ldsB = lds + 8192;

  const int tid  = threadIdx.x;
  const int lane = tid & 63, wv = tid >> 6;
  const int row0 = blockIdx.y * 128, col0 = blockIdx.x * 128;

  const int rS = wv * 32 + (lane >> 3);
  const int sS = (lane & 7) ^ (lane >> 3);

  const int lr = lane & 15, lk = lane >> 4;
  const int wr = wv >> 1, wc = wv & 1;
  const int swz = lr & 7;

  f32x4 acc[4][4] = {};

  for (int k0 = 0; k0 < K; k0 += 64) {
#pragma unroll
    for (int i = 0; i < 4; i++) {
      size_t ga = (size_t)(row0 + rS + i * 8) * K + k0 + sS * 8;
      gload_lds16(A + ga, ldsA + wv * 2048 + i * 512);
      size_t gb = (size_t)(col0 + rS + i * 8) * K + k0 + sS * 8;
      gload_lds16(Bt + gb, ldsB + wv * 2048 + i * 512);
    }
    __syncthreads();
#pragma unroll
    for (int half = 0; half < 2; half++) {
      const int k8 = half * 4 + lk;
      const int so = (k8 ^ swz) << 3;
      bf16x8 av[4], bv[4];
#pragma unroll
      for (int m = 0; m < 4; m++)
        av[m] = *(const bf16x8*)&ldsA[(wr * 64 + m * 16 + lr) * 64 + so];
#pragma unroll
      for (int n = 0; n < 4; n++)
        bv[n] = *(const bf16x8*)&ldsB[(wc * 64 + n * 16 + lr) * 64 + so];
#pragma unroll
      for (int m = 0; m < 4; m++)
#pragma unroll
        for (int n = 0; n < 4; n++)
          acc[m][n] = __builtin_amdgcn_mfma_f32_16x16x32_bf16(av[m], bv[n], acc[m][n], 0, 0, 0);
    }
    __syncthreads();
  }

  if (ACT == 2) {
    __shared__ float csum[64];
    if (tid < 64) csum[tid] = 0.f;
    __syncthreads();
#pragma unroll
    for (int n = 0; n < 4; n++) {
      int col = col0 + wc * 64 + n * 16 + lr;
      if (col < N) {
        float bi = bias[col];
        float local = 0.f;
#pragma unroll
        for (int m = 0; m < 4; m++)
#pragma unroll
          for (int g = 0; g < 4; g++) {
            int row = row0 + wr * 64 + m * 16 + lk * 4 + g;
            if (row < M) local += tanhf(acc[m][n][g] + bi);
          }
        atomicAdd(&csum[col], local);
      }
    }
    __syncthreads();
    if (tid < 64) atomicAdd(&Cf[tid], csum[tid]);
    return;
  }

  if (ACT == 3) {
    float su = 1.f / (1.f + expf(-skipp[0]));
#pragma unroll
    for (int n = 0; n < 4; n++) {
      int col = col0 + wc * 64 + n * 16 + lr;
      float bi = bias[col];
#pragma unroll
      for (int m = 0; m < 4; m++)
#pragma unroll
        for (int g = 0; g < 4; g++) {
          int row = row0 + wr * 64 + m * 16 + lk * 4 + g;
          float v = 0.f;
          if (row < M)
            v = su * (acc[m][n][g] + bi) + (1.f - su) * b2f(xprev[(size_t)row * 256 + col]);
          Cb[(size_t)row * ldcb + col] = f2b(v);
        }
    }
    return;
  }

#pragma unroll
  for (int n = 0; n < 4; n++) {
    int col = col0 + wc * 64 + n * 16 + lr;
    bool cok = col < N;
    float bi = cok ? bias[col] : 0.f;
#pragma unroll
    for (int m = 0; m < 4; m++) {
#pragma unroll
      for (int g = 0; g < 4; g++) {
        int row = row0 + wr * 64 + m * 16 + lk * 4 + g;
        float v = acc[m][n][g] + bi;
        if (ACT == 1) v = fmaxf(v, 0.f);
        if (cok) {
          if (Cf && row < M) Cf[(size_t)row * ldcf + col] = v;
          if (Cb) Cb[(size_t)row * ldcb + col] = f2b(row < M ? v : 0.f);
        }
      }
    }
  }
}

// ============ prep kernels ============
__global__ void conv_pad(const float* __restrict__ in, unsigned short* __restrict__ out,
                         int M, int C, int total)
{
  int t = blockIdx.x * 256 + threadIdx.x;
  if (t >= total) return;
  int r = t / C;
  out[t] = (r < M) ? f2b(in[t]) : 0;
}

__global__ void transp_conv(const float* __restrict__ W, int ldw, int coloff,
                            unsigned short* __restrict__ Bt, int K, int N, int total)
{
  int t = blockIdx.x * 256 + threadIdx.x;
  if (t >= total) return;
  int n = t / K, k = t - n * K;
  Bt[t] = (n < N) ? f2b(W[(size_t)k * ldw + coloff + n]) : 0;
}

__global__ void comb_w_t(const float* __restrict__ Wkqv, int coloff,
                         const float* __restrict__ Wh, unsigned short* __restrict__ Bt)
{
  int t = blockIdx.x * 256 + threadIdx.x;  // n*256 + c
  int n = t >> 8, c = t & 255;
  int hh = n >> 6, e = n & 63;
  float acc = 0.f;
  for (int d = 0; d < 64; d++)
    acc += Wkqv[(size_t)c * 768 + coloff + hh * 64 + d] * Wh[hh * 4096 + d * 64 + e];
  Bt[t] = f2b(acc);
}

__global__ void comb_b(const float* __restrict__ bkqv, int coloff,
                       const float* __restrict__ Wh, float* __restrict__ bout)
{
  int j = threadIdx.x;
  int hh = j >> 6, e = j & 63;
  float acc = 0.f;
  for (int d = 0; d < 64; d++)
    acc += bkqv[coloff + hh * 64 + d] * Wh[hh * 4096 + d * 64 + e];
  bout[j] = acc;
}

__global__ void copy_f32(const float* __restrict__ src, float* __restrict__ dst, int n)
{
  int t = blockIdx.x * 256 + threadIdx.x;
  if (t < n) dst[t] = src[t];
}

// ============ CSR build ============
__global__ void hist_dst(const int* __restrict__ ei, int ne, int* __restrict__ cnt)
{
  int t = blockIdx.x * 256 + threadIdx.x;
  if (t < ne) atomicAdd(&cnt[ei[ne + t]], 1);
}

// phase 1: per-chunk sums. grid = 3*NCH blocks.
__global__ __launch_bounds__(256)
void scan_partial(const int* __restrict__ cnt, int* __restrict__ csums)
{
  int b = blockIdx.x;
  int rel = b / NCH, ch = b - rel * NCH;
  const int* c = cnt + (size_t)rel * NU;
  int t = threadIdx.x;
  int i0 = ch * CHUNK + t * 8;
  int s = 0;
#pragma unroll
  for (int j = 0; j < 8; j++) { int i = i0 + j; if (i < NU) s += c[i]; }
  __shared__ int ps[256];
  ps[t] = s;
  __syncthreads();
  for (int d = 128; d > 0; d >>= 1) { if (t < d) ps[t] += ps[t + d]; __syncthreads(); }
  if (t == 0) csums[b] = ps[0];
}

// phase 2: scan the 20 chunk sums per relation; write totals at rs[NU]
__global__ void scan_mid(const int* __restrict__ csums, int* __restrict__ coffs,
                         int* __restrict__ rs)
{
  int r = threadIdx.x;
  if (r >= 3) return;
  int run = 0;
  for (int ch = 0; ch < NCH; ch++) { coffs[r * NCH + ch] = run; run += csums[r * NCH + ch]; }
  rs[(size_t)r * NUP + NU] = run;
}

// phase 3: per-chunk exclusive prefix with chunk offset. grid = 3*NCH blocks.
__global__ __launch_bounds__(256)
void scan_final(const int* __restrict__ cnt, const int* __restrict__ coffs,
                int* __restrict__ rs)
{
  int b = blockIdx.x;
  int rel = b / NCH, ch = b - rel * NCH;
  const int* c = cnt + (size_t)rel * NU;
  int* r = rs + (size_t)rel * NUP;
  int t = threadIdx.x;
  int i0 = ch * CHUNK + t * 8;
  int loc[8]; int s = 0;
#pragma unroll
  for (int j = 0; j < 8; j++) { int i = i0 + j; loc[j] = (i < NU) ? c[i] : 0; s += loc[j]; }
  __shared__ int ps[256];
  ps[t] = s;
  __syncthreads();
  for (int d = 1; d < 256; d <<= 1) {
    int o = (t >= d) ? ps[t - d] : 0;
    __syncthreads();
    ps[t] += o;
    __syncthreads();
  }
  int run = coffs[b] + ps[t] - s;   // exclusive across block+chunks
#pragma unroll
  for (int j = 0; j < 8; j++) { int i = i0 + j; if (i < NU) { r[i] = run; run += loc[j]; } }
}

// ============ HAN ============
__global__ void han_alsd(const float* __restrict__ h,
                         const float* __restrict__ a_s1, const float* __restrict__ a_d1,
                         const float* __restrict__ a_s2, const float* __restrict__ a_d2,
                         float* __restrict__ als1, float* __restrict__ ald1,
                         float* __restrict__ als2, float* __restrict__ ald2)
{
  int t = blockIdx.x * 256 + threadIdx.x;
  if (t >= NU * NHEAD) return;
  int n = t >> 2, hh = t & 3;
  const float* hp = h + (size_t)n * 64 + hh * 16;
  float s1 = 0, d1 = 0, s2 = 0, d2 = 0;
#pragma unroll
  for (int d = 0; d < 16; d++) {
    float v = hp[d];
    s1 += v * a_s1[hh * 16 + d]; d1 += v * a_d1[hh * 16 + d];
    s2 += v * a_s2[hh * 16 + d]; d2 += v * a_d2[hh * 16 + d];
  }
  als1[t] = s1; ald1[t] = d1; als2[t] = s2; ald2[t] = d2;
}

__global__ void han_fill(const int* __restrict__ ei, int ne,
                         const float* __restrict__ als, const float* __restrict__ ald,
                         const int* __restrict__ rs, int* __restrict__ cur,
                         int* __restrict__ esrc, float* __restrict__ aev)
{
  int t = blockIdx.x * 256 + threadIdx.x;
  if (t >= ne * 4) return;
  int e = t >> 2, hh = t & 3;
  int s = ei[e], d = ei[ne + e];
  float al = als[s * 4 + hh] + ald[d * 4 + hh];
  al = (al >= 0.f) ? al : 0.2f * al;
  float ex = expf(al);
  int pos = 0;
  if (hh == 0) pos = rs[d] + atomicAdd(&cur[d], 1);
  pos = __shfl(pos, 0, 4);
  aev[pos * 4 + hh] = ex;
  if (hh == 0) esrc[pos] = s;
}

// one wave per dst row; softmax denom in-register; writes relu'd bf16
__global__ __launch_bounds__(256)
void han_gather(const int* __restrict__ rs, const int* __restrict__ esrc,
                const float* __restrict__ aev, const float* __restrict__ h,
                unsigned short* __restrict__ obf)
{
  int gid = blockIdx.x * 256 + threadIdx.x;
  int wid = gid >> 6, lane = gid & 63;
  if (wid >= NUP) return;
  int head = lane >> 4;
  int beg = 0, end = 0;
  if (wid < NU) { beg = rs[wid]; end = rs[wid + 1]; }
  float asum = 0.f;
  for (int i = beg; i < end; i++) asum += aev[i * 4 + head];
  float inv = 1.f / (asum + 1e-16f);
  float a = 0.f;
  for (int i = beg; i < end; i++)
    a += aev[i * 4 + head] * inv * h[(size_t)esrc[i] * 64 + lane];
  obf[(size_t)wid * 64 + lane] = f2b(fmaxf(a, 0.f));
}

__global__ void sem_final2(const float* __restrict__ colpart2,
                           const float* __restrict__ q_sem, float* __restrict__ semv)
{
  int t = threadIdx.x;            // 128
  int j = t & 63;
  __shared__ float sv[128];
  sv[t] = colpart2[t] * q_sem[j] * (1.0f / NU);
  __syncthreads();
  if (t == 0) {
    float s0 = 0, s1 = 0;
    for (int i = 0; i < 64; i++) { s0 += sv[i]; s1 += sv[64 + i]; }
    float m = fmaxf(s0, s1);
    float e0 = expf(s0 - m), e1 = expf(s1 - m);
    semv[0] = e0 / (e0 + e1); semv[1] = e1 / (e0 + e1);
  }
}

// ============ HGT ============
__global__ void hgt_fill(const int* __restrict__ ei, int ne,
                         const unsigned short* __restrict__ qb,
                         const unsigned short* __restrict__ kb, int ks, int voff,
                         const float* __restrict__ p,
                         const int* __restrict__ rs, int* __restrict__ cur,
                         int* __restrict__ esrc, float* __restrict__ aev)
{
  int t = blockIdx.x * 256 + threadIdx.x;
  if (t >= ne * 4) return;
  int e = t >> 2, hh = t & 3;
  int s = ei[e], d = ei[ne + e];
  const uint4* qv = (const uint4*)(qb + (size_t)d * 768 + 256 + hh * 64);
  const uint4* kv = (const uint4*)(kb + (size_t)s * ks + hh * 64);
  float acc = 0.f;
#pragma unroll
  for (int i = 0; i < 8; i++) {
    uint4 a = qv[i], b = kv[i];
    unsigned int aw[4] = {a.x, a.y, a.z, a.w};
    unsigned int bw[4] = {b.x, b.y, b.z, b.w};
#pragma unroll
    for (int u = 0; u < 4; u++) {
      acc += b2f((unsigned short)(aw[u] & 0xffff)) * b2f((unsigned short)(bw[u] & 0xffff));
      acc += b2f((unsigned short)(aw[u] >> 16))    * b2f((unsigned short)(bw[u] >> 16));
    }
  }
  float ex = expf(acc * p[hh] * 0.125f);
  int pos = 0;
  if (hh == 0) pos = rs[d] + atomicAdd(&cur[d], 1);
  pos = __shfl(pos, 0, 4);
  aev[pos * 4 + hh] = ex;
  if (hh == 0) esrc[pos] = voff + s * ks;
}

// one wave per dst row (256 cols, 4/lane); fused softmax + gelu + bf16 out
__global__ __launch_bounds__(256)
void hgt_gather(const int* __restrict__ rs, const int* __restrict__ esrc,
                const float* __restrict__ aev, const unsigned short* __restrict__ vbase,
                unsigned short* __restrict__ houtb)
{
  int gid = blockIdx.x * 256 + threadIdx.x;
  int wid = gid >> 6, lane = gid & 63;
  if (wid >= NUP) return;
  int head = lane >> 4;
  int beg = 0, end = 0;
  if (wid < NU) { beg = rs[wid]; end = rs[wid + 1]; }
  float asum = 0.f;
  for (int i = beg; i < end; i++) asum += aev[i * 4 + head];
  float inv = 1.f / (asum + 1e-16f);
  float a0 = 0, a1 = 0, a2 = 0, a3 = 0;
  for (int i = beg; i < end; i++) {
    float w = aev[i * 4 + head] * inv;
    const ushort4 v = *(const ushort4*)(vbase + (size_t)esrc[i] + lane * 4);
    a0 += b2f(v.x) * w; a1 += b2f(v.y) * w; a2 += b2f(v.z) * w; a3 += b2f(v.w) * w;
  }
  ushort4 o;
  o.x = f2b(0.5f * a0 * (1.f + erff(a0 * 0.70710678118654752f)));
  o.y = f2b(0.5f * a1 * (1.f + erff(a1 * 0.70710678118654752f)));
  o.z = f2b(0.5f * a2 * (1.f + erff(a2 * 0.70710678118654752f)));
  o.w = f2b(0.5f * a3 * (1.f + erff(a3 * 0.70710678118654752f)));
  *(ushort4*)(houtb + (size_t)wid * 256 + lane * 4) = o;
}

// ============ epilogues ============
__global__ void fill_ref_b(const unsigned short* __restrict__ obf1,
                           const unsigned short* __restrict__ obf2,
                           const float* __restrict__ semv, unsigned short* __restrict__ afinb)
{
  int t = blockIdx.x * 256 + threadIdx.x;  // n*64 + j
  if (t >= NU * 64) return;
  int n = t >> 6, j = t & 63;
  float v = semv[0] * b2f(obf1[t]) + semv[1] * b2f(obf2[t]);  // already relu'd
  afinb[(size_t)n * 320 + 256 + j] = f2b(v);
}

// ------------------------------------------------------------------
extern "C" void kernel_launch(void* const* d_in, const int* in_sizes, int n_in,
                              void* d_out, int out_size, void* d_ws, size_t ws_size,
                              hipStream_t stream)
{
  (void)in_sizes; (void)n_in; (void)out_size; (void)ws_size;
  const float* x_user     = (const float*)d_in[0];
  const float* x_drug     = (const float*)d_in[1];
  const float* x_user_ref = (const float*)d_in[2];
  const int*   ei_du      = (const int*)d_in[4];
  const int*   ei_uu      = (const int*)d_in[5];
  const int*   ei_r1      = (const int*)d_in[6];
  const int*   ei_r2      = (const int*)d_in[7];
  const float* W_han      = (const float*)d_in[8];
  const float* b_han      = (const float*)d_in[9];
  const float* a_src_r1   = (const float*)d_in[10];
  const float* a_dst_r1   = (const float*)d_in[11];
  const float* a_src_r2   = (const float*)d_in[12];
  const float* a_dst_r2   = (const float*)d_in[13];
  const float* Wk_sem     = (const float*)d_in[14];
  const float* bk_sem     = (const float*)d_in[15];
  const float* q_sem      = (const float*)d_in[16];
  const float* W_in_user  = (const float*)d_in[17];
  const float* b_in_user  = (const float*)d_in[18];
  const float* W_in_drug  = (const float*)d_in[19];
  const float* b_in_drug  = (const float*)d_in[20];
  const float* W_kqv_user = (const float*)d_in[21];
  const float* b_kqv_user = (const float*)d_in[22];
  const float* W_kqv_drug = (const float*)d_in[23];
  const float* b_kqv_drug = (const float*)d_in[24];
  const float* Wk_du      = (const float*)d_in[28];
  const float* Wv_du      = (const float*)d_in[29];
  const float* p_du       = (const float*)d_in[30];
  const float* Wk_uu      = (const float*)d_in[31];
  const float* Wv_uu      = (const float*)d_in[32];
  const float* p_uu       = (const float*)d_in[33];
  const float* W_out_user = (const float*)d_in[34];
  const float* b_out_user = (const float*)d_in[35];
  const float* skip_user  = (const float*)d_in[38];
  const float* W_fin      = (const float*)d_in[40];
  const float* b_fin      = (const float*)d_in[41];
  float* out = (float*)d_out;

  // ---------------- workspace ----------------
  char* base = (char*)d_ws;
  size_t off = 0;
  auto alloc = [&](size_t bytes) { char* p = base + off; off += (bytes + 255) & ~(size_t)255; return p; };

  float* h       = (float*)alloc((size_t)NU * 64 * 4);
  float* als1    = (float*)alloc((size_t)NU * 4 * 4);
  float* ald1    = (float*)alloc((size_t)NU * 4 * 4);
  float* als2    = (float*)alloc((size_t)NU * 4 * 4);
  float* ald2    = (float*)alloc((size_t)NU * 4 * 4);
  float* colpart2= (float*)alloc(128 * 4);
  float* semv    = (float*)alloc(64);
  float* ball_u  = (float*)alloc(768 * 4);
  float* ball_d  = (float*)alloc(512 * 4);

  // CSR arrays: cnt[3][NU], rs[3][NUP], chunk sums/offsets
  int* cnt   = (int*)alloc((size_t)3 * NU * 4);
  int* rs    = (int*)alloc((size_t)3 * NUP * 4);
  int* csums = (int*)alloc((size_t)3 * NCH * 4);
  int* coffs = (int*)alloc((size_t)3 * NCH * 4);
  int* esrcH = (int*)alloc((size_t)2 * NEDGE * 4);
  float* aevH= (float*)alloc((size_t)2 * NEDGE * 4 * 4);
  int* esrc1 = (int*)alloc((size_t)NEDGE * 4);
  float* aev1= (float*)alloc((size_t)NEDGE * 4 * 4);
  int* esrc2 = (int*)alloc((size_t)NEDGE * 4);
  float* aev2= (float*)alloc((size_t)NEDGE * 4 * 4);

  unsigned short* obf1 = (unsigned short*)alloc((size_t)NUP * 64 * 2);
  unsigned short* obf2 = (unsigned short*)alloc((size_t)NUP * 64 * 2);

  // qukvb [NUP][768] (k'|q|v') and kvdb [NDP][512] (k'|v') — contiguous pair
  unsigned short* qukvb = (unsigned short*)alloc((size_t)NUP * 768 * 2);
  unsigned short* kvdb  = (unsigned short*)alloc((size_t)NDP * 512 * 2);

  unsigned short* xub2d = (unsigned short*)alloc((size_t)NUP * 256 * 2);  // relu(in-gemm) user
  unsigned short* xdb2d = (unsigned short*)alloc((size_t)NDP * 256 * 2);  // relu(in-gemm) drug

  // houtb bf16; earlier aliased by xrb (dead after HAN h-gemm)
  unsigned short* houtb = (unsigned short*)alloc((size_t)NUP * 256 * 2);
  unsigned short* xrb   = houtb;

  // afinb bf16 [NUP][320]; earlier aliased by xub/xdb (dead after input gemms)
  unsigned short* afinb = (unsigned short*)alloc((size_t)NUP * 320 * 2);
  unsigned short* xub   = afinb;
  unsigned short* xdb   = afinb + (size_t)NUP * 128;

  // weights (bf16, transposed)
  unsigned short* Btu_in  = (unsigned short*)alloc(256 * 128 * 2);
  unsigned short* Btd_in  = (unsigned short*)alloc(256 * 128 * 2);
  unsigned short* Btall_u = (unsigned short*)alloc(768 * 256 * 2);
  unsigned short* Btall_d = (unsigned short*)alloc(512 * 256 * 2);
  unsigned short* Bto     = (unsigned short*)alloc(256 * 256 * 2);
  unsigned short* Btf     = (unsigned short*)alloc(256 * 320 * 2);
  unsigned short* Bth     = (unsigned short*)alloc(128 * 128 * 2);
  unsigned short* BtWk    = (unsigned short*)alloc(128 * 64 * 2);

  const int B = 256;
  dim3 blk(B);
  auto g1 = [](size_t n) { return dim3((unsigned)((n + 255) / 256)); };

  // ===== prep: converts + weight transforms =====
  conv_pad<<<g1((size_t)NUP * 128), blk, 0, stream>>>(x_user, xub, NU, 128, NUP * 128);
  conv_pad<<<g1((size_t)NDP * 128), blk, 0, stream>>>(x_drug, xdb, ND, 128, NDP * 128);
  conv_pad<<<g1((size_t)NUP * 128), blk, 0, stream>>>(x_user_ref, xrb, NU, 128, NUP * 128);

  transp_conv<<<g1(256 * 128), blk, 0, stream>>>(W_in_user, 256, 0, Btu_in, 128, 256, 256 * 128);
  transp_conv<<<g1(256 * 128), blk, 0, stream>>>(W_in_drug, 256, 0, Btd_in, 128, 256, 256 * 128);
  transp_conv<<<g1(256 * 256), blk, 0, stream>>>(W_kqv_user, 768, 256, Btall_u + 256 * 256, 256, 256, 256 * 256);
  transp_conv<<<g1(256 * 256), blk, 0, stream>>>(W_out_user, 256, 0, Bto, 256, 256, 256 * 256);
  transp_conv<<<g1(256 * 320), blk, 0, stream>>>(W_fin, 256, 0, Btf, 320, 256, 256 * 320);
  transp_conv<<<g1(128 * 128), blk, 0, stream>>>(W_han, 64, 0, Bth, 128, 64, 128 * 128);
  transp_conv<<<g1(128 * 64), blk, 0, stream>>>(Wk_sem, 64, 0, BtWk, 64, 64, 128 * 64);

  comb_w_t<<<256, blk, 0, stream>>>(W_kqv_user, 0,   Wk_uu, Btall_u);
  comb_w_t<<<256, blk, 0, stream>>>(W_kqv_user, 512, Wv_uu, Btall_u + 512 * 256);
  comb_w_t<<<256, blk, 0, stream>>>(W_kqv_drug, 0,   Wk_du, Btall_d);
  comb_w_t<<<256, blk, 0, stream>>>(W_kqv_drug, 512, Wv_du, Btall_d + 256 * 256);
  comb_b<<<1, blk, 0, stream>>>(b_kqv_user, 0,   Wk_uu, ball_u);
  copy_f32<<<1, blk, 0, stream>>>(b_kqv_user + 256, ball_u + 256, 256);
  comb_b<<<1, blk, 0, stream>>>(b_kqv_user, 512, Wv_uu, ball_u + 512);
  comb_b<<<1, blk, 0, stream>>>(b_kqv_drug, 0,   Wk_du, ball_d);
  comb_b<<<1, blk, 0, stream>>>(b_kqv_drug, 512, Wv_du, ball_d + 256);

  // ===== CSR build (hierarchical scan) =====
  hipMemsetAsync(cnt, 0, (size_t)3 * NU * 4, stream);
  hist_dst<<<g1(NEDGE), blk, 0, stream>>>(ei_du, NEDGE, cnt);
  hist_dst<<<g1(NEDGE), blk, 0, stream>>>(ei_uu, NEDGE, cnt);
  hist_dst<<<g1(NEDGE), blk, 0, stream>>>(ei_r1, NEDGE, cnt + NU);
  hist_dst<<<g1(NEDGE), blk, 0, stream>>>(ei_r2, NEDGE, cnt + 2 * NU);
  scan_partial<<<3 * NCH, blk, 0, stream>>>(cnt, csums);
  scan_mid<<<1, 64, 0, stream>>>(csums, coffs, rs);
  scan_final<<<3 * NCH, blk, 0, stream>>>(cnt, coffs, rs);
  hipMemsetAsync(cnt, 0, (size_t)3 * NU * 4, stream);   // reuse as cursors
  hipMemsetAsync(colpart2, 0, 128 * 4, stream);

  // ===== HAN branch =====
  gemm_bf16<0><<<dim3(1, NUP / 128), blk, 0, stream>>>(
      xrb, Bth, b_han, h, 64, (unsigned short*)nullptr, 0, NU, 64, 128, nullptr, nullptr);

  han_alsd<<<g1((size_t)NU * 4), blk, 0, stream>>>(
      h, a_src_r1, a_dst_r1, a_src_r2, a_dst_r2, als1, ald1, als2, ald2);

  han_fill<<<g1((size_t)NEDGE * 4), blk, 0, stream>>>(ei_r1, NEDGE, als1, ald1,
      rs + NUP, cnt + NU, esrc1, aev1);
  han_fill<<<g1((size_t)NEDGE * 4), blk, 0, stream>>>(ei_r2, NEDGE, als2, ald2,
      rs + 2 * NUP, cnt + 2 * NU, esrc2, aev2);
  han_gather<<<g1((size_t)NUP * 64), blk, 0, stream>>>(rs + NUP, esrc1, aev1, h, obf1);
  han_gather<<<g1((size_t)NUP * 64), blk, 0, stream>>>(rs + 2 * NUP, esrc2, aev2, h, obf2);

  gemm_bf16<2><<<dim3(1, NUP / 128), blk, 0, stream>>>(
      obf1, BtWk, bk_sem, colpart2, 0, (unsigned short*)nullptr, 0, NU, 64, 64, nullptr, nullptr);
  gemm_bf16<2><<<dim3(1, NUP / 128), blk, 0, stream>>>(
      obf2, BtWk, bk_sem, colpart2 + 64, 0, (unsigned short*)nullptr, 0, NU, 64, 64, nullptr, nullptr);
  sem_final2<<<1, 128, 0, stream>>>(colpart2, q_sem, semv);

  // ===== HGT GEMMs =====
  gemm_bf16<1><<<dim3(2, NUP / 128), blk, 0, stream>>>(
      xub, Btu_in, b_in_user, (float*)nullptr, 0, xub2d, 256, NU, 256, 128, nullptr, nullptr);
  gemm_bf16<1><<<dim3(2, NDP / 128), blk, 0, stream>>>(
      xdb, Btd_in, b_in_drug, (float*)nullptr, 0, xdb2d, 256, ND, 256, 128, nullptr, nullptr);

  gemm_bf16<0><<<dim3(6, NUP / 128), blk, 0, stream>>>(
      xub2d, Btall_u, ball_u, (float*)nullptr, 0, qukvb, 768, NU, 768, 256, nullptr, nullptr);
  gemm_bf16<0><<<dim3(4, NDP / 128), blk, 0, stream>>>(
      xdb2d, Btall_d, ball_d, (float*)nullptr, 0, kvdb, 512, ND, 512, 256, nullptr, nullptr);

  // ===== HGT attention: fill (q.k + exp) then gather (softmax+PV+gelu) =====
  hgt_fill<<<g1((size_t)NEDGE * 4), blk, 0, stream>>>(ei_du, NEDGE,
      qukvb, kvdb, 512, NUP * 768 + 256, p_du, rs, cnt, esrcH, aevH);
  hgt_fill<<<g1((size_t)NEDGE * 4), blk, 0, stream>>>(ei_uu, NEDGE,
      qukvb, qukvb, 768, 512, p_uu, rs, cnt, esrcH, aevH);
  hgt_gather<<<g1((size_t)NUP * 64), blk, 0, stream>>>(rs, esrcH, aevH, qukvb, houtb);

  // ===== output head =====
  hipMemsetAsync(afinb + (size_t)NU * 320, 0, (size_t)(NUP - NU) * 320 * 2, stream);
  gemm_bf16<3><<<dim3(2, NUP / 128), blk, 0, stream>>>(
      houtb, Bto, b_out_user, (float*)nullptr, 0, afinb, 320, NU, 256, 256, skip_user, xub2d);
  fill_ref_b<<<g1((size_t)NU * 64), blk, 0, stream>>>(obf1, obf2, semv, afinb);

  gemm_bf16<0><<<dim3(2, NUP / 128), blk, 0, stream>>>(
      afinb, Btf, b_fin, out, 256, (unsigned short*)nullptr, 0, NU, 256, 320, nullptr, nullptr);
}

// Round 6
// 445.570 us; speedup vs baseline: 3.2060x; 1.0725x over previous
//
#include <hip/hip_runtime.h>
#include <hip/hip_bf16.h>

#define NU 40000
#define ND 20000
#define NUP 40064   // 313*128
#define NDP 20096   // 157*128
#define HIDC 256
#define NHEAD 4
#define NEDGE 80000
#define CHUNK 2048
#define NCH 20      // ceil(NU/CHUNK)

typedef __attribute__((ext_vector_type(8))) short bf16x8;
typedef __attribute__((ext_vector_type(8))) unsigned short u16x8;
typedef __attribute__((ext_vector_type(4))) float f32x4;

static __device__ __forceinline__ float b2f(unsigned short u) {
  union { unsigned int u; float f; } x; x.u = (unsigned int)u << 16; return x.f;
}
static __device__ __forceinline__ unsigned short f2b(float f) {
  union { float f; unsigned int u; } x; x.f = f;
  unsigned int r = x.u + 0x7FFFu + ((x.u >> 16) & 1u);
  return (unsigned short)(r >> 16);
}

static __device__ __forceinline__ void gload_lds16(const void* g, void* l) {
  __builtin_amdgcn_global_load_lds((const __attribute__((address_space(1))) unsigned int*)g,
                                   (__attribute__((address_space(3))) unsigned int*)l, 16, 0, 0);
}

// ============ bf16 MFMA GEMM: C = act(A @ Bt^T + bias) ============
// A: [Mpad][K] bf16. Bt: [Npad][K] bf16. 1D grid = ceil(Mblk/8)*8*Nx, 256 thr.
// XCD-colocating swizzle: all Nx col-blocks of a row-panel share id mod 8.
// ACT 0: none, 1: relu, 2: tanh+colsum->atomicAdd(Cf[col]),
// ACT 3: skip-mix epilogue: Cb = f2b(su*(acc+bias) + (1-su)*b2f(xprev)) (bf16)
template<int ACT>
__global__ __launch_bounds__(256)
void gemm_bf16(const unsigned short* __restrict__ A,
               const unsigned short* __restrict__ Bt,
               const float* __restrict__ bias,
               float* __restrict__ Cf, int ldcf,
               unsigned short* __restrict__ Cb, int ldcb,
               int M, int N, int K, int Mblk,
               const float* __restrict__ skipp,
               const unsigned short* __restrict__ xprev)
{
  __shared__ __attribute__((aligned(128))) unsigned char smem[34816];
  unsigned short* ldsA = (unsigned short*)smem;
  unsigned short* ldsB = ldsA + 8192;
  float* ldsE = (float*)smem;

  const int Nx = (N + 127) >> 7;
  const int S = Nx << 3;
  const int flat = blockIdx.x;
  const int jj = flat % S, kq = flat / S;
  const int bx = jj >> 3, by = (kq << 3) + (jj & 7);
  if (by >= Mblk) return;

  const int tid  = threadIdx.x;
  const int lane = tid & 63, wv = tid >> 6;
  const int row0 = by * 128, col0 = bx * 128;

  const int rS = wv * 32 + (lane >> 3);
  const int sS = (lane & 7) ^ (lane >> 3);

  const int lr = lane & 15, lk = lane >> 4;
  const int wr = wv >> 1, wc = wv & 1;
  const int swz = lr & 7;

  f32x4 acc[4][4] = {};

  for (int k0 = 0; k0 < K; k0 += 64) {
#pragma unroll
    for (int i = 0; i < 4; i++) {
      size_t ga = (size_t)(row0 + rS + i * 8) * K + k0 + sS * 8;
      gload_lds16(A + ga, ldsA + wv * 2048 + i * 512);
      size_t gb = (size_t)(col0 + rS + i * 8) * K + k0 + sS * 8;
      gload_lds16(Bt + gb, ldsB + wv * 2048 + i * 512);
    }
    __syncthreads();
#pragma unroll
    for (int half = 0; half < 2; half++) {
      const int k8 = half * 4 + lk;
      const int so = (k8 ^ swz) << 3;
      bf16x8 av[4], bv[4];
#pragma unroll
      for (int m = 0; m < 4; m++)
        av[m] = *(const bf16x8*)&ldsA[(wr * 64 + m * 16 + lr) * 64 + so];
#pragma unroll
      for (int n = 0; n < 4; n++)
        bv[n] = *(const bf16x8*)&ldsB[(wc * 64 + n * 16 + lr) * 64 + so];
#pragma unroll
      for (int m = 0; m < 4; m++)
#pragma unroll
        for (int n = 0; n < 4; n++)
          acc[m][n] = __builtin_amdgcn_mfma_f32_16x16x32_bf16(av[m], bv[n], acc[m][n], 0, 0, 0);
    }
    __syncthreads();
  }

  if (ACT == 2) {
    __shared__ float csum[64];
    if (tid < 64) csum[tid] = 0.f;
    __syncthreads();
#pragma unroll
    for (int n = 0; n < 4; n++) {
      int col = col0 + wc * 64 + n * 16 + lr;
      if (col < N) {
        float bi = bias[col];
        float local = 0.f;
#pragma unroll
        for (int m = 0; m < 4; m++)
#pragma unroll
          for (int g = 0; g < 4; g++) {
            int row = row0 + wr * 64 + m * 16 + lk * 4 + g;
            if (row < M) local += tanhf(acc[m][n][g] + bi);
          }
        atomicAdd(&csum[col], local);
      }
    }
    __syncthreads();
    if (tid < 64) atomicAdd(&Cf[tid], csum[tid]);
    return;
  }

  // ===== LDS-staged vectorized epilogue (two 64-row chunks) =====
  float su = 0.f;
  if (ACT == 3) su = 1.f / (1.f + expf(-skipp[0]));
  const int ES = 134;   // f32 row stride: 4-row delta = 536 words = 24 mod 32 banks

#pragma unroll
  for (int ch = 0; ch < 2; ch++) {
    __syncthreads();
    if (wr == ch) {
#pragma unroll
      for (int n = 0; n < 4; n++) {
        int col = col0 + wc * 64 + n * 16 + lr;
        float bi = (col < N) ? bias[col] : 0.f;
#pragma unroll
        for (int m = 0; m < 4; m++) {
#pragma unroll
          for (int g = 0; g < 4; g++) {
            int lrow = m * 16 + lk * 4 + g;          // 0..63 within chunk
            int row = row0 + ch * 64 + lrow;
            float v = acc[m][n][g] + bi;
            if (ACT == 1) v = fmaxf(v, 0.f);
            if (ACT == 3) v = su * v + (1.f - su) * b2f(xprev[(size_t)row * 256 + col]);
            if (row >= M) v = 0.f;
            ldsE[lrow * ES + wc * 64 + n * 16 + lr] = v;
          }
        }
      }
    }
    __syncthreads();
#pragma unroll
    for (int i = 0; i < 4; i++) {
      int c = tid + i * 256;            // 0..1023 over 64 rows x 16 col-chunks
      int lrow = c >> 4, cc = c & 15;
      int row = row0 + ch * 64 + lrow;
      int colb = cc * 8;
      float v[8];
#pragma unroll
      for (int q = 0; q < 8; q++) v[q] = ldsE[lrow * ES + colb + q];
      if (Cb) {
        u16x8 o;
#pragma unroll
        for (int q = 0; q < 8; q++) o[q] = f2b(v[q]);
        *(u16x8*)(Cb + (size_t)row * ldcb + col0 + colb) = o;
      }
      if (Cf && row < M) {
        int col = col0 + colb;
        if (col < N)
          *(float4*)&Cf[(size_t)row * ldcf + col] = make_float4(v[0], v[1], v[2], v[3]);
        if (col + 4 < N)
          *(float4*)&Cf[(size_t)row * ldcf + col + 4] = make_float4(v[4], v[5], v[6], v[7]);
      }
    }
  }
}

// ============ prep kernels ============
__global__ void conv_pad(const float* __restrict__ in, unsigned short* __restrict__ out,
                         int M, int C, int total)
{
  int t = blockIdx.x * 256 + threadIdx.x;
  if (t >= total) return;
  int r = t / C;
  out[t] = (r < M) ? f2b(in[t]) : 0;
}

__global__ void transp_conv(const float* __restrict__ W, int ldw, int coloff,
                            unsigned short* __restrict__ Bt, int K, int N, int total)
{
  int t = blockIdx.x * 256 + threadIdx.x;
  if (t >= total) return;
  int n = t / K, k = t - n * K;
  Bt[t] = (n < N) ? f2b(W[(size_t)k * ldw + coloff + n]) : 0;
}

__global__ void comb_w_t(const float* __restrict__ Wkqv, int coloff,
                         const float* __restrict__ Wh, unsigned short* __restrict__ Bt)
{
  int t = blockIdx.x * 256 + threadIdx.x;  // n*256 + c
  int n = t >> 8, c = t & 255;
  int hh = n >> 6, e = n & 63;
  float acc = 0.f;
  for (int d = 0; d < 64; d++)
    acc += Wkqv[(size_t)c * 768 + coloff + hh * 64 + d] * Wh[hh * 4096 + d * 64 + e];
  Bt[t] = f2b(acc);
}

__global__ void comb_b(const float* __restrict__ bkqv, int coloff,
                       const float* __restrict__ Wh, float* __restrict__ bout)
{
  int j = threadIdx.x;
  int hh = j >> 6, e = j & 63;
  float acc = 0.f;
  for (int d = 0; d < 64; d++)
    acc += bkqv[coloff + hh * 64 + d] * Wh[hh * 4096 + d * 64 + e];
  bout[j] = acc;
}

__global__ void copy_f32(const float* __restrict__ src, float* __restrict__ dst, int n)
{
  int t = blockIdx.x * 256 + threadIdx.x;
  if (t < n) dst[t] = src[t];
}

// ============ CSR build ============
__global__ void hist_dst(const int* __restrict__ ei, int ne, int* __restrict__ cnt)
{
  int t = blockIdx.x * 256 + threadIdx.x;
  if (t < ne) atomicAdd(&cnt[ei[ne + t]], 1);
}

__global__ __launch_bounds__(256)
void scan_partial(const int* __restrict__ cnt, int* __restrict__ csums)
{
  int b = blockIdx.x;
  int rel = b / NCH, ch = b - rel * NCH;
  const int* c = cnt + (size_t)rel * NU;
  int t = threadIdx.x;
  int i0 = ch * CHUNK + t * 8;
  int s = 0;
#pragma unroll
  for (int j = 0; j < 8; j++) { int i = i0 + j; if (i < NU) s += c[i]; }
  __shared__ int ps[256];
  ps[t] = s;
  __syncthreads();
  for (int d = 128; d > 0; d >>= 1) { if (t < d) ps[t] += ps[t + d]; __syncthreads(); }
  if (t == 0) csums[b] = ps[0];
}

__global__ void scan_mid(const int* __restrict__ csums, int* __restrict__ coffs,
                         int* __restrict__ rs)
{
  int r = threadIdx.x;
  if (r >= 3) return;
  int run = 0;
  for (int ch = 0; ch < NCH; ch++) { coffs[r * NCH + ch] = run; run += csums[r * NCH + ch]; }
  rs[(size_t)r * NUP + NU] = run;
}

__global__ __launch_bounds__(256)
void scan_final(const int* __restrict__ cnt, const int* __restrict__ coffs,
                int* __restrict__ rs)
{
  int b = blockIdx.x;
  int rel = b / NCH, ch = b - rel * NCH;
  const int* c = cnt + (size_t)rel * NU;
  int* r = rs + (size_t)rel * NUP;
  int t = threadIdx.x;
  int i0 = ch * CHUNK + t * 8;
  int loc[8]; int s = 0;
#pragma unroll
  for (int j = 0; j < 8; j++) { int i = i0 + j; loc[j] = (i < NU) ? c[i] : 0; s += loc[j]; }
  __shared__ int ps[256];
  ps[t] = s;
  __syncthreads();
  for (int d = 1; d < 256; d <<= 1) {
    int o = (t >= d) ? ps[t - d] : 0;
    __syncthreads();
    ps[t] += o;
    __syncthreads();
  }
  int run = coffs[b] + ps[t] - s;
#pragma unroll
  for (int j = 0; j < 8; j++) { int i = i0 + j; if (i < NU) { r[i] = run; run += loc[j]; } }
}

// ============ HAN ============
__global__ void han_alsd(const float* __restrict__ h,
                         const float* __restrict__ a_s1, const float* __restrict__ a_d1,
                         const float* __restrict__ a_s2, const float* __restrict__ a_d2,
                         float* __restrict__ als1, float* __restrict__ ald1,
                         float* __restrict__ als2, float* __restrict__ ald2)
{
  int t = blockIdx.x * 256 + threadIdx.x;
  if (t >= NU * NHEAD) return;
  int n = t >> 2, hh = t & 3;
  const float* hp = h + (size_t)n * 64 + hh * 16;
  float s1 = 0, d1 = 0, s2 = 0, d2 = 0;
#pragma unroll
  for (int d = 0; d < 16; d++) {
    float v = hp[d];
    s1 += v * a_s1[hh * 16 + d]; d1 += v * a_d1[hh * 16 + d];
    s2 += v * a_s2[hh * 16 + d]; d2 += v * a_d2[hh * 16 + d];
  }
  als1[t] = s1; ald1[t] = d1; als2[t] = s2; ald2[t] = d2;
}

__global__ void han_fill(const int* __restrict__ ei, int ne,
                         const float* __restrict__ als, const float* __restrict__ ald,
                         const int* __restrict__ rs, int* __restrict__ cur,
                         int* __restrict__ esrc, float* __restrict__ aev)
{
  int t = blockIdx.x * 256 + threadIdx.x;
  if (t >= ne * 4) return;
  int e = t >> 2, hh = t & 3;
  int s = ei[e], d = ei[ne + e];
  float al = als[s * 4 + hh] + ald[d * 4 + hh];
  al = (al >= 0.f) ? al : 0.2f * al;
  float ex = expf(al);
  int pos = 0;
  if (hh == 0) pos = rs[d] + atomicAdd(&cur[d], 1);
  pos = __shfl(pos, 0, 4);
  aev[pos * 4 + hh] = ex;
  if (hh == 0) esrc[pos] = s;
}

__global__ __launch_bounds__(256)
void han_gather(const int* __restrict__ rs, const int* __restrict__ esrc,
                const float* __restrict__ aev, const float* __restrict__ h,
                unsigned short* __restrict__ obf)
{
  int gid = blockIdx.x * 256 + threadIdx.x;
  int wid = gid >> 6, lane = gid & 63;
  if (wid >= NUP) return;
  int head = lane >> 4;
  int beg = 0, end = 0;
  if (wid < NU) { beg = rs[wid]; end = rs[wid + 1]; }
  float asum = 0.f;
  for (int i = beg; i < end; i++) asum += aev[i * 4 + head];
  float inv = 1.f / (asum + 1e-16f);
  float a = 0.f;
  for (int i = beg; i < end; i++)
    a += aev[i * 4 + head] * inv * h[(size_t)esrc[i] * 64 + lane];
  obf[(size_t)wid * 64 + lane] = f2b(fmaxf(a, 0.f));
}

__global__ void sem_final2(const float* __restrict__ colpart2,
                           const float* __restrict__ q_sem, float* __restrict__ semv)
{
  int t = threadIdx.x;            // 128
  int j = t & 63;
  __shared__ float sv[128];
  sv[t] = colpart2[t] * q_sem[j] * (1.0f / NU);
  __syncthreads();
  if (t == 0) {
    float s0 = 0, s1 = 0;
    for (int i = 0; i < 64; i++) { s0 += sv[i]; s1 += sv[64 + i]; }
    float m = fmaxf(s0, s1);
    float e0 = expf(s0 - m), e1 = expf(s1 - m);
    semv[0] = e0 / (e0 + e1); semv[1] = e1 / (e0 + e1);
  }
}

// ============ HGT ============
__global__ void hgt_fill(const int* __restrict__ ei, int ne,
                         const unsigned short* __restrict__ qb,
                         const unsigned short* __restrict__ kb, int ks, int voff,
                         const float* __restrict__ p,
                         const int* __restrict__ rs, int* __restrict__ cur,
                         int* __restrict__ esrc, float* __restrict__ aev)
{
  int t = blockIdx.x * 256 + threadIdx.x;
  if (t >= ne * 4) return;
  int e = t >> 2, hh = t & 3;
  int s = ei[e], d = ei[ne + e];
  const uint4* qv = (const uint4*)(qb + (size_t)d * 768 + 256 + hh * 64);
  const uint4* kv = (const uint4*)(kb + (size_t)s * ks + hh * 64);
  float acc = 0.f;
#pragma unroll
  for (int i = 0; i < 8; i++) {
    uint4 a = qv[i], b = kv[i];
    unsigned int aw[4] = {a.x, a.y, a.z, a.w};
    unsigned int bw[4] = {b.x, b.y, b.z, b.w};
#pragma unroll
    for (int u = 0; u < 4; u++) {
      acc += b2f((unsigned short)(aw[u] & 0xffff)) * b2f((unsigned short)(bw[u] & 0xffff));
      acc += b2f((unsigned short)(aw[u] >> 16))    * b2f((unsigned short)(bw[u] >> 16));
    }
  }
  float ex = expf(acc * p[hh] * 0.125f);
  int pos = 0;
  if (hh == 0) pos = rs[d] + atomicAdd(&cur[d], 1);
  pos = __shfl(pos, 0, 4);
  aev[pos * 4 + hh] = ex;
  if (hh == 0) esrc[pos] = voff + s * ks;
}

__global__ __launch_bounds__(256)
void hgt_gather(const int* __restrict__ rs, const int* __restrict__ esrc,
                const float* __restrict__ aev, const unsigned short* __restrict__ vbase,
                unsigned short* __restrict__ houtb)
{
  int gid = blockIdx.x * 256 + threadIdx.x;
  int wid = gid >> 6, lane = gid & 63;
  if (wid >= NUP) return;
  int head = lane >> 4;
  int beg = 0, end = 0;
  if (wid < NU) { beg = rs[wid]; end = rs[wid + 1]; }
  float asum = 0.f;
  for (int i = beg; i < end; i++) asum += aev[i * 4 + head];
  float inv = 1.f / (asum + 1e-16f);
  float a0 = 0, a1 = 0, a2 = 0, a3 = 0;
  for (int i = beg; i < end; i++) {
    float w = aev[i * 4 + head] * inv;
    const ushort4 v = *(const ushort4*)(vbase + (size_t)esrc[i] + lane * 4);
    a0 += b2f(v.x) * w; a1 += b2f(v.y) * w; a2 += b2f(v.z) * w; a3 += b2f(v.w) * w;
  }
  ushort4 o;
  o.x = f2b(0.5f * a0 * (1.f + erff(a0 * 0.70710678118654752f)));
  o.y = f2b(0.5f * a1 * (1.f + erff(a1 * 0.70710678118654752f)));
  o.z = f2b(0.5f * a2 * (1.f + erff(a2 * 0.70710678118654752f)));
  o.w = f2b(0.5f * a3 * (1.f + erff(a3 * 0.70710678118654752f)));
  *(ushort4*)(houtb + (size_t)wid * 256 + lane * 4) = o;
}

// ============ epilogues ============
__global__ void fill_ref_b(const unsigned short* __restrict__ obf1,
                           const unsigned short* __restrict__ obf2,
                           const float* __restrict__ semv, unsigned short* __restrict__ afinb)
{
  int t = blockIdx.x * 256 + threadIdx.x;  // n*64 + j
  if (t >= NU * 64) return;
  int n = t >> 6, j = t & 63;
  float v = semv[0] * b2f(obf1[t]) + semv[1] * b2f(obf2[t]);  // already relu'd
  afinb[(size_t)n * 320 + 256 + j] = f2b(v);
}

// ------------------------------------------------------------------
extern "C" void kernel_launch(void* const* d_in, const int* in_sizes, int n_in,
                              void* d_out, int out_size, void* d_ws, size_t ws_size,
                              hipStream_t stream)
{
  (void)in_sizes; (void)n_in; (void)out_size; (void)ws_size;
  const float* x_user     = (const float*)d_in[0];
  const float* x_drug     = (const float*)d_in[1];
  const float* x_user_ref = (const float*)d_in[2];
  const int*   ei_du      = (const int*)d_in[4];
  const int*   ei_uu      = (const int*)d_in[5];
  const int*   ei_r1      = (const int*)d_in[6];
  const int*   ei_r2      = (const int*)d_in[7];
  const float* W_han      = (const float*)d_in[8];
  const float* b_han      = (const float*)d_in[9];
  const float* a_src_r1   = (const float*)d_in[10];
  const float* a_dst_r1   = (const float*)d_in[11];
  const float* a_src_r2   = (const float*)d_in[12];
  const float* a_dst_r2   = (const float*)d_in[13];
  const float* Wk_sem     = (const float*)d_in[14];
  const float* bk_sem     = (const float*)d_in[15];
  const float* q_sem      = (const float*)d_in[16];
  const float* W_in_user  = (const float*)d_in[17];
  const float* b_in_user  = (const float*)d_in[18];
  const float* W_in_drug  = (const float*)d_in[19];
  const float* b_in_drug  = (const float*)d_in[20];
  const float* W_kqv_user = (const float*)d_in[21];
  const float* b_kqv_user = (const float*)d_in[22];
  const float* W_kqv_drug = (const float*)d_in[23];
  const float* b_kqv_drug = (const float*)d_in[24];
  const float* Wk_du      = (const float*)d_in[28];
  const float* Wv_du      = (const float*)d_in[29];
  const float* p_du       = (const float*)d_in[30];
  const float* Wk_uu      = (const float*)d_in[31];
  const float* Wv_uu      = (const float*)d_in[32];
  const float* p_uu       = (const float*)d_in[33];
  const float* W_out_user = (const float*)d_in[34];
  const float* b_out_user = (const float*)d_in[35];
  const float* skip_user  = (const float*)d_in[38];
  const float* W_fin      = (const float*)d_in[40];
  const float* b_fin      = (const float*)d_in[41];
  float* out = (float*)d_out;

  // ---------------- workspace ----------------
  char* base = (char*)d_ws;
  size_t off = 0;
  auto alloc = [&](size_t bytes) { char* p = base + off; off += (bytes + 255) & ~(size_t)255; return p; };

  float* h       = (float*)alloc((size_t)NU * 64 * 4);
  float* als1    = (float*)alloc((size_t)NU * 4 * 4);
  float* ald1    = (float*)alloc((size_t)NU * 4 * 4);
  float* als2    = (float*)alloc((size_t)NU * 4 * 4);
  float* ald2    = (float*)alloc((size_t)NU * 4 * 4);
  float* colpart2= (float*)alloc(128 * 4);
  float* semv    = (float*)alloc(64);
  float* ball_u  = (float*)alloc(768 * 4);
  float* ball_d  = (float*)alloc(512 * 4);

  int* cnt   = (int*)alloc((size_t)3 * NU * 4);
  int* rs    = (int*)alloc((size_t)3 * NUP * 4);
  int* csums = (int*)alloc((size_t)3 * NCH * 4);
  int* coffs = (int*)alloc((size_t)3 * NCH * 4);
  int* esrcH = (int*)alloc((size_t)2 * NEDGE * 4);
  float* aevH= (float*)alloc((size_t)2 * NEDGE * 4 * 4);
  int* esrc1 = (int*)alloc((size_t)NEDGE * 4);
  float* aev1= (float*)alloc((size_t)NEDGE * 4 * 4);
  int* esrc2 = (int*)alloc((size_t)NEDGE * 4);
  float* aev2= (float*)alloc((size_t)NEDGE * 4 * 4);

  unsigned short* obf1 = (unsigned short*)alloc((size_t)NUP * 64 * 2);
  unsigned short* obf2 = (unsigned short*)alloc((size_t)NUP * 64 * 2);

  unsigned short* qukvb = (unsigned short*)alloc((size_t)NUP * 768 * 2);
  unsigned short* kvdb  = (unsigned short*)alloc((size_t)NDP * 512 * 2);

  unsigned short* xub2d = (unsigned short*)alloc((size_t)NUP * 256 * 2);
  unsigned short* xdb2d = (unsigned short*)alloc((size_t)NDP * 256 * 2);

  unsigned short* houtb = (unsigned short*)alloc((size_t)NUP * 256 * 2);
  unsigned short* xrb   = houtb;

  unsigned short* afinb = (unsigned short*)alloc((size_t)NUP * 320 * 2);
  unsigned short* xub   = afinb;
  unsigned short* xdb   = afinb + (size_t)NUP * 128;

  unsigned short* Btu_in  = (unsigned short*)alloc(256 * 128 * 2);
  unsigned short* Btd_in  = (unsigned short*)alloc(256 * 128 * 2);
  unsigned short* Btall_u = (unsigned short*)alloc(768 * 256 * 2);
  unsigned short* Btall_d = (unsigned short*)alloc(512 * 256 * 2);
  unsigned short* Bto     = (unsigned short*)alloc(256 * 256 * 2);
  unsigned short* Btf     = (unsigned short*)alloc(256 * 320 * 2);
  unsigned short* Bth     = (unsigned short*)alloc(128 * 128 * 2);
  unsigned short* BtWk    = (unsigned short*)alloc(128 * 64 * 2);

  const int B = 256;
  dim3 blk(B);
  auto g1 = [](size_t n) { return dim3((unsigned)((n + 255) / 256)); };
  auto gg = [](int N, int Mblk) {
    int Nx = (N + 127) / 128;
    return dim3((unsigned)(((Mblk + 7) / 8) * 8 * Nx));
  };

  // ===== prep: converts + weight transforms =====
  conv_pad<<<g1((size_t)NUP * 128), blk, 0, stream>>>(x_user, xub, NU, 128, NUP * 128);
  conv_pad<<<g1((size_t)NDP * 128), blk, 0, stream>>>(x_drug, xdb, ND, 128, NDP * 128);
  conv_pad<<<g1((size_t)NUP * 128), blk, 0, stream>>>(x_user_ref, xrb, NU, 128, NUP * 128);

  transp_conv<<<g1(256 * 128), blk, 0, stream>>>(W_in_user, 256, 0, Btu_in, 128, 256, 256 * 128);
  transp_conv<<<g1(256 * 128), blk, 0, stream>>>(W_in_drug, 256, 0, Btd_in, 128, 256, 256 * 128);
  transp_conv<<<g1(256 * 256), blk, 0, stream>>>(W_kqv_user, 768, 256, Btall_u + 256 * 256, 256, 256, 256 * 256);
  transp_conv<<<g1(256 * 256), blk, 0, stream>>>(W_out_user, 256, 0, Bto, 256, 256, 256 * 256);
  transp_conv<<<g1(256 * 320), blk, 0, stream>>>(W_fin, 256, 0, Btf, 320, 256, 256 * 320);
  transp_conv<<<g1(128 * 128), blk, 0, stream>>>(W_han, 64, 0, Bth, 128, 64, 128 * 128);
  transp_conv<<<g1(128 * 64), blk, 0, stream>>>(Wk_sem, 64, 0, BtWk, 64, 64, 128 * 64);

  comb_w_t<<<256, blk, 0, stream>>>(W_kqv_user, 0,   Wk_uu, Btall_u);
  comb_w_t<<<256, blk, 0, stream>>>(W_kqv_user, 512, Wv_uu, Btall_u + 512 * 256);
  comb_w_t<<<256, blk, 0, stream>>>(W_kqv_drug, 0,   Wk_du, Btall_d);
  comb_w_t<<<256, blk, 0, stream>>>(W_kqv_drug, 512, Wv_du, Btall_d + 256 * 256);
  comb_b<<<1, blk, 0, stream>>>(b_kqv_user, 0,   Wk_uu, ball_u);
  copy_f32<<<1, blk, 0, stream>>>(b_kqv_user + 256, ball_u + 256, 256);
  comb_b<<<1, blk, 0, stream>>>(b_kqv_user, 512, Wv_uu, ball_u + 512);
  comb_b<<<1, blk, 0, stream>>>(b_kqv_drug, 0,   Wk_du, ball_d);
  comb_b<<<1, blk, 0, stream>>>(b_kqv_drug, 512, Wv_du, ball_d + 256);

  // ===== CSR build =====
  hipMemsetAsync(cnt, 0, (size_t)3 * NU * 4, stream);
  hist_dst<<<g1(NEDGE), blk, 0, stream>>>(ei_du, NEDGE, cnt);
  hist_dst<<<g1(NEDGE), blk, 0, stream>>>(ei_uu, NEDGE, cnt);
  hist_dst<<<g1(NEDGE), blk, 0, stream>>>(ei_r1, NEDGE, cnt + NU);
  hist_dst<<<g1(NEDGE), blk, 0, stream>>>(ei_r2, NEDGE, cnt + 2 * NU);
  scan_partial<<<3 * NCH, blk, 0, stream>>>(cnt, csums);
  scan_mid<<<1, 64, 0, stream>>>(csums, coffs, rs);
  scan_final<<<3 * NCH, blk, 0, stream>>>(cnt, coffs, rs);
  hipMemsetAsync(cnt, 0, (size_t)3 * NU * 4, stream);
  hipMemsetAsync(colpart2, 0, 128 * 4, stream);

  // ===== HAN branch =====
  gemm_bf16<0><<<gg(64, 313), blk, 0, stream>>>(
      xrb, Bth, b_han, h, 64, (unsigned short*)nullptr, 0, NU, 64, 128, 313, nullptr, nullptr);

  han_alsd<<<g1((size_t)NU * 4), blk, 0, stream>>>(
      h, a_src_r1, a_dst_r1, a_src_r2, a_dst_r2, als1, ald1, als2, ald2);

  han_fill<<<g1((size_t)NEDGE * 4), blk, 0, stream>>>(ei_r1, NEDGE, als1, ald1,
      rs + NUP, cnt + NU, esrc1, aev1);
  han_fill<<<g1((size_t)NEDGE * 4), blk, 0, stream>>>(ei_r2, NEDGE, als2, ald2,
      rs + 2 * NUP, cnt + 2 * NU, esrc2, aev2);
  han_gather<<<g1((size_t)NUP * 64), blk, 0, stream>>>(rs + NUP, esrc1, aev1, h, obf1);
  han_gather<<<g1((size_t)NUP * 64), blk, 0, stream>>>(rs + 2 * NUP, esrc2, aev2, h, obf2);

  gemm_bf16<2><<<gg(64, 313), blk, 0, stream>>>(
      obf1, BtWk, bk_sem, colpart2, 0, (unsigned short*)nullptr, 0, NU, 64, 64, 313, nullptr, nullptr);
  gemm_bf16<2><<<gg(64, 313), blk, 0, stream>>>(
      obf2, BtWk, bk_sem, colpart2 + 64, 0, (unsigned short*)nullptr, 0, NU, 64, 64, 313, nullptr, nullptr);
  sem_final2<<<1, 128, 0, stream>>>(colpart2, q_sem, semv);

  // ===== HGT GEMMs =====
  gemm_bf16<1><<<gg(256, 313), blk, 0, stream>>>(
      xub, Btu_in, b_in_user, (float*)nullptr, 0, xub2d, 256, NU, 256, 128, 313, nullptr, nullptr);
  gemm_bf16<1><<<gg(256, 157), blk, 0, stream>>>(
      xdb, Btd_in, b_in_drug, (float*)nullptr, 0, xdb2d, 256, ND, 256, 128, 157, nullptr, nullptr);

  gemm_bf16<0><<<gg(768, 313), blk, 0, stream>>>(
      xub2d, Btall_u, ball_u, (float*)nullptr, 0, qukvb, 768, NU, 768, 256, 313, nullptr, nullptr);
  gemm_bf16<0><<<gg(512, 157), blk, 0, stream>>>(
      xdb2d, Btall_d, ball_d, (float*)nullptr, 0, kvdb, 512, ND, 512, 256, 157, nullptr, nullptr);

  // ===== HGT attention =====
  hgt_fill<<<g1((size_t)NEDGE * 4), blk, 0, stream>>>(ei_du, NEDGE,
      qukvb, kvdb, 512, NUP * 768 + 256, p_du, rs, cnt, esrcH, aevH);
  hgt_fill<<<g1((size_t)NEDGE * 4), blk, 0, stream>>>(ei_uu, NEDGE,
      qukvb, qukvb, 768, 512, p_uu, rs, cnt, esrcH, aevH);
  hgt_gather<<<g1((size_t)NUP * 64), blk, 0, stream>>>(rs, esrcH, aevH, qukvb, houtb);

  // ===== output head =====
  hipMemsetAsync(afinb + (size_t)NU * 320, 0, (size_t)(NUP - NU) * 320 * 2, stream);
  gemm_bf16<3><<<gg(256, 313), blk, 0, stream>>>(
      houtb, Bto, b_out_user, (float*)nullptr, 0, afinb, 320, NU, 256, 256, 313, skip_user, xub2d);
  fill_ref_b<<<g1((size_t)NU * 64), blk, 0, stream>>>(obf1, obf2, semv, afinb);

  gemm_bf16<0><<<gg(256, 313), blk, 0, stream>>>(
      afinb, Btf, b_fin, out, 256, (unsigned short*)nullptr, 0, NU, 256, 320, 313, nullptr, nullptr);
}